// Round 13
// baseline (455.880 us; speedup 1.0000x reference)
//
#include <hip/hip_runtime.h>
#include <math.h>

// ---------------------------------------------------------------------------
// GraphTransformer, bf16 MFMA. Round 13: LN fused into producer GEMMs via
// tile-counter last-block epilogue (kills 4 add_ln dispatches); layer-0 small
// flash merged into the big flash dispatch (tail blocks).
// NL=2, H=4, C=512, IN=256, F=16, B=256, NC=47, DH=128
// ---------------------------------------------------------------------------

typedef unsigned short bf16_t;
typedef __attribute__((ext_vector_type(8))) short bf16x8_t;
typedef __attribute__((ext_vector_type(4))) float f32x4_t;

#define M_BIG 4096
#define M_CAT 4352  // 4096 + 256
#define NSPLIT 4

__device__ __forceinline__ bf16_t f2bf(float f) {
  union { float f; unsigned u; } v; v.f = f;
  unsigned r = v.u + 0x7FFFu + ((v.u >> 16) & 1u);
  return (bf16_t)(r >> 16);
}
__device__ __forceinline__ float bf2f(bf16_t u) {
  union { unsigned u; float f; } v; v.u = ((unsigned)u) << 16; return v.f;
}
__device__ __forceinline__ unsigned cvtpk(float lo, float hi) {
  unsigned r;
  asm("v_cvt_pk_bf16_f32 %0, %1, %2" : "=v"(r) : "v"(lo), "v"(hi));
  return r;
}
__device__ __forceinline__ void gload16(const void* g, void* l) {
  __builtin_amdgcn_global_load_lds(
      (const __attribute__((address_space(1))) unsigned int*)g,
      (__attribute__((address_space(3))) unsigned int*)l, 16, 0, 0);
}

// Q pre-scale: 1/sqrt(128) * log2(e)  (softmax runs in log2 domain)
#define QSCALE (0.08838834764831845f * 1.4426950408889634f)

// ---------------------------------------------------------------------------
// GEMM: C[M,N] = A[M,K] @ W[N,K]^T + epilogue. A,W bf16; accum fp32.
// MODE 3: Cb = relu(acc + b)                    (ffn1)
// MODE 4: Cb = (acc + b + res[m,n]) * (m<M1?rowa:rowa2)  (ffn2+resid+nmask)
// MODE 5: qkv: n<512 -> Cb[m,1024]*QSCALE; <1024 -> Cb; >=1024 -> Vt[n-1024,m]
// MODE 6: merged embedding (rows 0..M_CAT = fcat -> nmask1|nmask0;
//         rows M_CAT.. = aggFb -> (acc + b*rowb)*rowc)
// MODE 7: Cb = acc + b (raw); then tile-counter: LAST column-block of each
//         64-row group computes Hout = LN(res + Cb) * lng + lnb.  N must be
//         512 (gridDim.y * 64). Counters cnt[] must be zeroed per launch.
// ---------------------------------------------------------------------------
template <int BM, int BN, int MODE, bool SPLIT>
__global__ __launch_bounds__(256) void mgemm(
    const bf16_t* __restrict__ A, const bf16_t* __restrict__ A2,
    const bf16_t* __restrict__ W, const float* __restrict__ bias,
    const bf16_t* __restrict__ res, const float* __restrict__ rowa,
    const float* __restrict__ rowa2, const float* __restrict__ rowb,
    const float* __restrict__ rowc,
    bf16_t* __restrict__ Cb, bf16_t* __restrict__ Vt,
    int M, int M1, int N, int K,
    bf16_t* __restrict__ Hout, int* __restrict__ cnt) {
  constexpr int FM = BM / 32, FN = BN / 32;
  constexpr int NCH = (BM + BN) / 16;
  constexpr int CPW = NCH / 4;
  __shared__ bf16_t lds[2][(BM + BN) * 32];
  __shared__ int lastflag;
  const int t = threadIdx.x;
  const int w = t >> 6, lane = t & 63;
  const int g = lane >> 4, li = lane & 15;
  const int bm = blockIdx.x * BM, bn = blockIdx.y * BN;
  const int wr = (w >> 1) * (BM / 2), wc = (w & 1) * (BN / 2);
  f32x4_t acc[FM][FN] = {};

  auto stage = [&](int buf, int k0) {
#pragma unroll
    for (int c0 = 0; c0 < CPW; ++c0) {
      const int c = w * CPW + c0;
      const int row = c * 16 + (lane >> 2);
      const int gk = k0 + (lane & 3) * 8;
      const bf16_t* src;
      if (row < BM) {
        const int grow = bm + row;
        if (MODE == 6) {
          src = (grow < M_CAT) ? (A + (size_t)grow * K + gk)
                               : (A2 + (size_t)(grow - M_CAT) * K + gk);
        } else if (SPLIT) {
          src = (gk < 512) ? (A + (size_t)grow * 512 + gk)
                           : (A2 + (size_t)grow * 512 + (gk - 512));
        } else {
          src = A + (size_t)grow * K + gk;
        }
      } else {
        src = W + (size_t)(bn + row - BM) * K + gk;
      }
      gload16(src, &lds[buf][c * 512]);
    }
  };

  const int nk = K / 32;
  stage(0, 0);
  for (int ks = 0; ks < nk; ++ks) {
    __syncthreads();
    if (ks + 1 < nk) stage((ks + 1) & 1, (ks + 1) * 32);
    const bf16_t* As = &lds[ks & 1][0];
    const bf16_t* Bs = &lds[ks & 1][BM * 32];
    bf16x8_t af[FM], bfr[FN];
#pragma unroll
    for (int i = 0; i < FM; ++i)
      af[i] = *(const bf16x8_t*)(As + (wr + i * 16 + li) * 32 + g * 8);
#pragma unroll
    for (int j = 0; j < FN; ++j)
      bfr[j] = *(const bf16x8_t*)(Bs + (wc + j * 16 + li) * 32 + g * 8);
#pragma unroll
    for (int i = 0; i < FM; ++i)
#pragma unroll
      for (int j = 0; j < FN; ++j)
        acc[i][j] = __builtin_amdgcn_mfma_f32_16x16x32_bf16(
            af[i], bfr[j], acc[i][j], 0, 0, 0);
  }

  // epilogue: D frag: col n = li, row m = g*4 + reg (verified layout)
#pragma unroll
  for (int i = 0; i < FM; ++i) {
    const int mb = bm + wr + i * 16 + g * 4;
#pragma unroll
    for (int j = 0; j < FN; ++j) {
      const int n = bn + wc + j * 16 + li;
      if (MODE == 5) {
        const float bb = bias[n];
        if (n < 512) {
#pragma unroll
          for (int r = 0; r < 4; ++r)
            Cb[(size_t)(mb + r) * 1024 + n] = f2bf((acc[i][j][r] + bb) * QSCALE);
        } else if (n < 1024) {
#pragma unroll
          for (int r = 0; r < 4; ++r)
            Cb[(size_t)(mb + r) * 1024 + n] = f2bf(acc[i][j][r] + bb);
        } else {
          ushort4 o;
          o.x = f2bf(acc[i][j][0] + bb); o.y = f2bf(acc[i][j][1] + bb);
          o.z = f2bf(acc[i][j][2] + bb); o.w = f2bf(acc[i][j][3] + bb);
          *(ushort4*)(Vt + (size_t)(n - 1024) * M + mb) = o;
        }
      } else {
#pragma unroll
        for (int r = 0; r < 4; ++r) {
          const int m = mb + r;
          const float v = acc[i][j][r];
          if (MODE == 3) Cb[(size_t)m * N + n] = f2bf(fmaxf(v + bias[n], 0.f));
          if (MODE == 4) {
            const float ra = (m < M1) ? rowa[m] : rowa2[m - M1];
            Cb[(size_t)m * N + n] =
                f2bf((v + bias[n] + bf2f(res[(size_t)m * N + n])) * ra);
          }
          if (MODE == 6) {
            float val;
            if (m < M1) val = (v + bias[n]) * rowa[m];
            else if (m < M_CAT) val = (v + bias[n]) * rowa2[m - M1];
            else {
              const int mm = m - M_CAT;
              val = (v + bias[n] * rowb[mm]) * rowc[mm];
            }
            Cb[(size_t)m * N + n] = f2bf(val);
          }
          if (MODE == 7) Cb[(size_t)m * N + n] = f2bf(v + bias[n]);
        }
      }
    }
  }

  if (MODE == 7) {
    // rowa = LN gamma, rowa2 = LN beta, res = residual X, Hout = LN output.
    __threadfence();   // agent-scope release: tile visible across XCDs
    __syncthreads();   // all waves' stores + fences done
    if (t == 0)
      lastflag = (atomicAdd(&cnt[blockIdx.x], 1) == (int)gridDim.y - 1);
    __syncthreads();
    if (lastflag) {
      __threadfence();  // acquire side
      float g8[8], b8[8];
#pragma unroll
      for (int e = 0; e < 8; ++e) {
        g8[e] = rowa[lane * 8 + e];
        b8[e] = rowa2[lane * 8 + e];
      }
      for (int rr = 0; rr < 16; ++rr) {
        const int row = bm + w * 16 + rr;
        const bf16x8_t xv =
            *(const bf16x8_t*)(res + (size_t)row * 512 + lane * 8);
        const bf16x8_t yv =
            *(const bf16x8_t*)(Cb + (size_t)row * 512 + lane * 8);
        float x[8];
        float s = 0.f, ss = 0.f;
#pragma unroll
        for (int e = 0; e < 8; ++e) {
          x[e] = bf2f((bf16_t)xv[e]) + bf2f((bf16_t)yv[e]);
          s += x[e];
          ss += x[e] * x[e];
        }
#pragma unroll
        for (int o = 1; o < 64; o <<= 1) {
          s += __shfl_xor(s, o);
          ss += __shfl_xor(ss, o);
        }
        const float mean = s * (1.f / 512.f);
        const float rstd = rsqrtf(ss * (1.f / 512.f) - mean * mean + 1e-5f);
        bf16x8_t ov;
#pragma unroll
        for (int e = 0; e < 8; ++e)
          ov[e] = (short)f2bf((x[e] - mean) * rstd * g8[e] + b8[e]);
        *(bf16x8_t*)(Hout + (size_t)row * 512 + lane * 8) = ov;
      }
    }
  }
}

// ---------------------------------------------------------------------------
// Flash attention, swapped-operand, double-buffered. NW waves; NQC q-frags
// per wave; two-pass PV (80KB LDS). Blocks >= nbig run the "tail" problem
// (qk2/vt2, N2 keys, direct write to attno2) -- used to fuse the layer-0
// n=256 attention into the big dispatch.
// ---------------------------------------------------------------------------
template <int NW, int NQC, int SPLITS>
__global__ __launch_bounds__(NW * 64) void flashT(
    const bf16_t* __restrict__ qk, const bf16_t* __restrict__ vt,
    bf16_t* __restrict__ attno, bf16_t* __restrict__ Ofb,
    float* __restrict__ Ml, int N, int VS,
    const bf16_t* __restrict__ qk2, const bf16_t* __restrict__ vt2,
    bf16_t* __restrict__ attno2, int nbig, int N2) {
  constexpr int QB = NW * NQC * 16;  // q rows per block
  constexpr int KCH = 16 / NW;       // staging chunks per wave (K and V each)
  __shared__ bf16_t Ks[2][64 * 128];
  __shared__ bf16_t Vs[2][128 * 64];
  __shared__ bf16_t Ps[NW][16 * 64];
  const int bid = blockIdx.x;
  int sp, h, qb, kvbase, nt;
  bool direct;
  const bf16_t *qkB, *vtB;
  bf16_t* attD;
  if (bid < nbig) {
    sp = bid % SPLITS;
    h = (bid / SPLITS) & 3;
    qb = bid / (4 * SPLITS);
    qkB = qk; vtB = vt;
    kvbase = sp * (N / SPLITS);
    nt = (N / SPLITS) >> 6;
    direct = (SPLITS == 1);
    attD = attno;
  } else {
    const int b2 = bid - nbig;
    sp = 0; h = b2 & 3; qb = 0;
    qkB = qk2; vtB = vt2;
    kvbase = 0;
    nt = N2 >> 6;
    direct = true;
    attD = attno2;
  }
  const int t = threadIdx.x, w = t >> 6, lane = t & 63;
  const int g = lane >> 4, li = lane & 15;

  bf16x8_t qf[NQC][4];
#pragma unroll
  for (int qc = 0; qc < NQC; ++qc) {
    const bf16_t* qrow =
        qkB + (size_t)(qb * QB + w * (NQC * 16) + qc * 16 + li) * 1024 + h * 128;
#pragma unroll
    for (int ks = 0; ks < 4; ++ks)
      qf[qc][ks] = *(const bf16x8_t*)(qrow + ks * 32 + g * 8);
  }

  // hoisted LDS byte offsets (xor-swizzled layout, round-2-verified)
  int koff[4], voff[2], pwoff[4];
#pragma unroll
  for (int ks = 0; ks < 4; ++ks)
    koff[ks] = li * 256 + (((ks * 4 + g) ^ (li & 7)) << 4);
#pragma unroll
  for (int ks = 0; ks < 2; ++ks)
    voff[ks] = li * 128 + (((ks * 4 + g) ^ (li & 7)) << 4);
#pragma unroll
  for (int mf = 0; mf < 4; ++mf)
    pwoff[mf] = li * 128 + (((mf * 2 + (g >> 1)) ^ (li & 7)) << 4) +
                ((g & 1) << 3);
  char* Pb = (char*)Ps + w * 2048;

  // running staging pointers (advance per tile)
  const bf16_t* kp[KCH];
  const bf16_t* vp[KCH];
#pragma unroll
  for (int i = 0; i < KCH; ++i) {
    const int c = w * KCH + i;
    const int rk = c * 4 + (lane >> 4);
    kp[i] = qkB + (size_t)(kvbase + rk) * 1024 + 512 + h * 128 +
            (((lane & 15) ^ (rk & 7)) * 8);
    const int rv = c * 8 + (lane >> 3);
    vp[i] = vtB + (size_t)(h * 128 + rv) * VS + kvbase +
            (((lane & 7) ^ (rv & 7)) * 8);
  }
  auto stage = [&](int buf) {
#pragma unroll
    for (int i = 0; i < KCH; ++i) {
      const int c = w * KCH + i;
      gload16(kp[i], &Ks[buf][c * 512]);
      kp[i] += (size_t)64 * 1024;
      gload16(vp[i], &Vs[buf][c * 512]);
      vp[i] += 64;
    }
  };

  f32x4_t acc[NQC][8] = {};
  float mrun[NQC], lrun[NQC];
#pragma unroll
  for (int qc = 0; qc < NQC; ++qc) { mrun[qc] = -1e30f; lrun[qc] = 0.f; }

  stage(0);
  for (int tt = 0; tt < nt; ++tt) {
    const int cur = tt & 1;
    __syncthreads();  // drains own stage loads (vmcnt(0)) -> cur resident
    if (tt + 1 < nt) stage(cur ^ 1);  // prefetch overlaps with compute below
    const char* Kb = (const char*)Ks + cur * 16384;
    const char* Vb = (const char*)Vs + cur * 16384;

    // S^T = K · Q^T : frag row kv = mf*16+g*4+r, col q = li (per qc)
    f32x4_t sf[NQC][4];
#pragma unroll
    for (int qc = 0; qc < NQC; ++qc)
#pragma unroll
      for (int mf = 0; mf < 4; ++mf) sf[qc][mf] = (f32x4_t){0.f, 0.f, 0.f, 0.f};
    __builtin_amdgcn_s_setprio(1);
#pragma unroll
    for (int ks = 0; ks < 4; ++ks) {
#pragma unroll
      for (int mf = 0; mf < 4; ++mf) {
        const bf16x8_t kf = *(const bf16x8_t*)(Kb + koff[ks] + mf * 4096);
#pragma unroll
        for (int qc = 0; qc < NQC; ++qc)
          sf[qc][mf] = __builtin_amdgcn_mfma_f32_16x16x32_bf16(
              kf, qf[qc][ks], sf[qc][mf], 0, 0, 0);
      }
    }
    __builtin_amdgcn_s_setprio(0);

    // online softmax (log2 domain); lane li owns q-rows (qc*16+li)
    float tmax[NQC];
#pragma unroll
    for (int qc = 0; qc < NQC; ++qc) {
      float tm = -1e30f;
#pragma unroll
      for (int mf = 0; mf < 4; ++mf)
#pragma unroll
        for (int r = 0; r < 4; ++r) tm = fmaxf(tm, sf[qc][mf][r]);
      tm = fmaxf(tm, __shfl_xor(tm, 16));
      tm = fmaxf(tm, __shfl_xor(tm, 32));
      tmax[qc] = tm;
    }
    float worst = tmax[0] - mrun[0];
#pragma unroll
    for (int qc = 1; qc < NQC; ++qc)
      worst = fmaxf(worst, tmax[qc] - mrun[qc]);
    if (!__all(worst <= 11.0f)) {  // defer-rescale (P bounded by 2^11)
#pragma unroll
      for (int qc = 0; qc < NQC; ++qc) {
        const float mnew = fmaxf(mrun[qc], tmax[qc]);
        const float fsc = exp2f(mrun[qc] - mnew);
        mrun[qc] = mnew;
        lrun[qc] *= fsc;
#pragma unroll
        for (int mf = 0; mf < 8; ++mf) acc[qc][mf] *= fsc;
      }
    }
#pragma unroll
    for (int qc = 0; qc < NQC; ++qc) {
      float lsum = 0.f;
#pragma unroll
      for (int mf = 0; mf < 4; ++mf)
#pragma unroll
        for (int r = 0; r < 4; ++r) {
          const float p = exp2f(sf[qc][mf][r] - mrun[qc]);
          sf[qc][mf][r] = p;
          lsum += p;
        }
      lsum += __shfl_xor(lsum, 16);
      lsum += __shfl_xor(lsum, 32);
      lrun[qc] += lsum;
    }

    // PV, one pass per qc: P -> per-wave LDS, then O^T += Vt · P^T.
    __builtin_amdgcn_s_setprio(1);
#pragma unroll
    for (int qc = 0; qc < NQC; ++qc) {
#pragma unroll
      for (int mf = 0; mf < 4; ++mf) {
        uint2 pv;
        pv.x = cvtpk(sf[qc][mf][0], sf[qc][mf][1]);
        pv.y = cvtpk(sf[qc][mf][2], sf[qc][mf][3]);
        *(uint2*)(Pb + pwoff[mf]) = pv;
      }
#pragma unroll
      for (int ks = 0; ks < 2; ++ks) {
        const bf16x8_t pf = *(const bf16x8_t*)(Pb + voff[ks]);
#pragma unroll
        for (int mf = 0; mf < 8; ++mf) {
          const bf16x8_t vf = *(const bf16x8_t*)(Vb + voff[ks] + mf * 2048);
          acc[qc][mf] = __builtin_amdgcn_mfma_f32_16x16x32_bf16(
              vf, pf, acc[qc][mf], 0, 0, 0);
        }
      }
    }
    __builtin_amdgcn_s_setprio(0);
  }

#pragma unroll
  for (int qc = 0; qc < NQC; ++qc) {
    const float invl = 1.f / lrun[qc];
    const int q = qb * QB + w * (NQC * 16) + qc * 16 + li;
    bf16_t* dst = direct ? (attD + (size_t)q * 512 + h * 128)
                         : (Ofb + ((size_t)sp * N + q) * 512 + h * 128);
#pragma unroll
    for (int mf = 0; mf < 8; ++mf) {
      ushort4 o;
      o.x = f2bf(acc[qc][mf][0] * invl); o.y = f2bf(acc[qc][mf][1] * invl);
      o.z = f2bf(acc[qc][mf][2] * invl); o.w = f2bf(acc[qc][mf][3] * invl);
      *(ushort4*)(dst + mf * 16 + g * 4) = o;
    }
    if (!direct && lane < 16) {
      float2 ml; ml.x = mrun[qc]; ml.y = lrun[qc];
      *(float2*)(Ml + ((size_t)(sp * 4 + h) * N + q) * 2) = ml;
    }
  }
}

// merge SPLITS normalized partials: w_s = l_s * 2^(m_s - m); out = Σ w_s O_s / Σ w_s
template <int SPLITS>
__global__ __launch_bounds__(256) void merge_attn(
    const bf16_t* __restrict__ Ofb, const float* __restrict__ Ml,
    bf16_t* __restrict__ attno, int N) {
  const int q = blockIdx.x, t = threadIdx.x;
#pragma unroll
  for (int half = 0; half < 2; ++half) {
    const int c = t + half * 256;
    const int h = c >> 7;
    float2 ml[SPLITS];
    float m = -1e30f;
#pragma unroll
    for (int s = 0; s < SPLITS; ++s) {
      ml[s] = ((const float2*)Ml)[(s * 4 + h) * N + q];
      m = fmaxf(m, ml[s].x);
    }
    float num = 0.f, den = 0.f;
#pragma unroll
    for (int s = 0; s < SPLITS; ++s) {
      const float wgt = ml[s].y * exp2f(ml[s].x - m);
      num += bf2f(Ofb[((size_t)s * N + q) * 512 + c]) * wgt;
      den += wgt;
    }
    attno[(size_t)q * 512 + c] = f2bf(num / den);
  }
}

// ---------------------------------------------------------------------------
// vectorized: 4 nodes per block, 64 lanes x float4 per node
__global__ __launch_bounds__(256) void agg_feats(
    const float* __restrict__ feats2, const int* __restrict__ nbm,
    const float* __restrict__ nm2, bf16_t* __restrict__ aggF,
    float* __restrict__ sw, float* __restrict__ invd) {
  const int node = blockIdx.x * 4 + (threadIdx.x >> 6);
  const int lane = threadIdx.x & 63;
  float4 acc = {0.f, 0.f, 0.f, 0.f};
  float ws = 0.f, nbs = 0.f;
#pragma unroll
  for (int j = 0; j < 16; ++j) {
    const float nb = (float)nbm[node * 16 + j];
    const float wj = nb * nm2[node * 16 + j];
    const float4 v =
        *(const float4*)(feats2 + (size_t)(node * 16 + j) * 256 + lane * 4);
    acc.x += wj * v.x; acc.y += wj * v.y;
    acc.z += wj * v.z; acc.w += wj * v.w;
    ws += wj;
    nbs += nb;
  }
  ushort4 o;
  o.x = f2bf(acc.x); o.y = f2bf(acc.y); o.z = f2bf(acc.z); o.w = f2bf(acc.w);
  *(ushort4*)(aggF + (size_t)node * 256 + lane * 4) = o;
  if (lane == 0) { sw[node] = ws; invd[node] = 1.f / fmaxf(nbs, 1.f); }
}

// vectorized: 4 nodes per block (one per wave), lane covers 8 cols (bf16x8)
__global__ __launch_bounds__(256) void agg_state(
    const bf16_t* __restrict__ src, const int* __restrict__ nbm,
    bf16_t* __restrict__ agg) {
  const int node = blockIdx.x * 4 + (threadIdx.x >> 6);
  const int lane = threadIdx.x & 63;
  float acc[8] = {};
  float nbs = 0.f;
#pragma unroll
  for (int j = 0; j < 16; ++j) {
    const float nb = (float)nbm[node * 16 + j];
    nbs += nb;
    const bf16x8_t v =
        *(const bf16x8_t*)(src + (size_t)(node * 16 + j) * 512 + lane * 8);
#pragma unroll
    for (int e = 0; e < 8; ++e) acc[e] += nb * bf2f((bf16_t)v[e]);
  }
  const float inv = 1.f / fmaxf(nbs, 1.f);
  bf16x8_t o;
#pragma unroll
  for (int e = 0; e < 8; ++e) o[e] = (short)f2bf(acc[e] * inv);
  *(bf16x8_t*)(agg + (size_t)node * 512 + lane * 8) = o;
}

// all fp32->bf16 conversions in one dispatch (float4-unit segments)
__global__ __launch_bounds__(256) void cvt_all(
    const float* __restrict__ s_emb, const float* __restrict__ s_sage,
    const float* __restrict__ s_qkv, const float* __restrict__ s_out,
    const float* __restrict__ s_f1, const float* __restrict__ s_f2,
    const float* __restrict__ s_ft0, const float* __restrict__ s_ft1,
    bf16_t* __restrict__ d_emb, bf16_t* __restrict__ d_sage,
    bf16_t* __restrict__ d_qkv, bf16_t* __restrict__ d_out,
    bf16_t* __restrict__ d_f1, bf16_t* __restrict__ d_f2,
    bf16_t* __restrict__ d_ft0, bf16_t* __restrict__ d_ft1) {
  int i = blockIdx.x * 256 + threadIdx.x;
  const float* s; bf16_t* d; int base;
  if (i < 32768)        { s = s_emb;  d = d_emb;  base = 0; }
  else if (i < 294912)  { s = s_sage; d = d_sage; base = 32768; }
  else if (i < 688128)  { s = s_qkv;  d = d_qkv;  base = 294912; }
  else if (i < 819200)  { s = s_out;  d = d_out;  base = 688128; }
  else if (i < 1081344) { s = s_f1;   d = d_f1;   base = 819200; }
  else if (i < 1343488) { s = s_f2;   d = d_f2;   base = 1081344; }
  else if (i < 1359872) { s = s_ft0;  d = d_ft0;  base = 1343488; }
  else                  { s = s_ft1;  d = d_ft1;  base = 1359872; }
  i -= base;
  const float4 v = ((const float4*)s)[i];
  ushort4 o;
  o.x = f2bf(v.x); o.y = f2bf(v.y); o.z = f2bf(v.z); o.w = f2bf(v.w);
  ((ushort4*)d)[i] = o;
}

__global__ __launch_bounds__(256) void cls_k(
    const bf16_t* __restrict__ s, const float* __restrict__ wc,
    const float* __restrict__ bc, float* __restrict__ out) {
  __shared__ float srow[512];
  const int m = blockIdx.x, t = threadIdx.x;
  srow[t] = bf2f(s[(size_t)m * 512 + t]);
  srow[t + 256] = bf2f(s[(size_t)m * 512 + 256 + t]);
  __syncthreads();
  if (t < 47) {
    float a = bc[t];
    const float* wr = wc + (size_t)t * 512;
    for (int k = 0; k < 512; ++k) a += srow[k] * wr[k];
    out[(size_t)m * 47 + t] = a;
  }
}

// ---------------------------------------------------------------------------
extern "C" void kernel_launch(void* const* d_in, const int* in_sizes, int n_in,
                              void* d_out, int out_size, void* d_ws,
                              size_t ws_size, hipStream_t stream) {
  const float* feats0 = (const float*)d_in[0];
  const float* feats1 = (const float*)d_in[1];
  const float* feats2 = (const float*)d_in[2];
  const float* nmask0 = (const float*)d_in[3];
  const float* nmask1 = (const float*)d_in[4];
  const float* nmask2 = (const float*)d_in[5];
  const int* nbmask0 = (const int*)d_in[6];
  const int* nbmask1 = (const int*)d_in[7];
  const float* emb_w = (const float*)d_in[8];
  const float* emb_b = (const float*)d_in[9];
  const float* sage_w = (const float*)d_in[10];
  const float* sage_b = (const float*)d_in[11];
  const float* qkv_w = (const float*)d_in[12];
  const float* qkv_b = (const float*)d_in[13];
  const float* out_w = (const float*)d_in[14];
  const float* out_b = (const float*)d_in[15];
  const float* n1_g = (const float*)d_in[16];
  const float* n1_b = (const float*)d_in[17];
  const float* n2_g = (const float*)d_in[18];
  const float* n2_b = (const float*)d_in[19];
  const float* ffn_w1 = (const float*)d_in[20];
  const float* ffn_b1 = (const float*)d_in[21];
  const float* ffn_w2 = (const float*)d_in[22];
  const float* ffn_b2 = (const float*)d_in[23];
  const float* cls_w = (const float*)d_in[24];
  const float* cls_b = (const float*)d_in[25];
  float* out = (float*)d_out;

  size_t off = 0;
  auto alloc = [&](size_t bytes) {
    void* r = (char*)d_ws + off;
    off += (bytes + 255) & ~(size_t)255;
    return r;
  };
  bf16_t* wemb = (bf16_t*)alloc((size_t)512 * 256 * 2);
  bf16_t* wsage = (bf16_t*)alloc((size_t)2 * 512 * 1024 * 2);
  bf16_t* wqkv = (bf16_t*)alloc((size_t)2 * 1536 * 512 * 2);
  bf16_t* wout = (bf16_t*)alloc((size_t)2 * 512 * 512 * 2);
  bf16_t* wf1 = (bf16_t*)alloc((size_t)2 * 1024 * 512 * 2);
  bf16_t* wf2 = (bf16_t*)alloc((size_t)2 * 512 * 1024 * 2);
  bf16_t* fcat = (bf16_t*)alloc((size_t)M_CAT * 256 * 2);   // feats1|feats0
  bf16_t* s_cat = (bf16_t*)alloc((size_t)2 * M_CAT * 512 * 2);
  bf16_t* agg_cat = s_cat + (size_t)M_CAT * 512;
  bf16_t* scat_o = (bf16_t*)alloc((size_t)M_CAT * 512 * 2); // s1b|s0b
  bf16_t* aggFb = (bf16_t*)alloc((size_t)4096 * 256 * 2);
  float* swv = (float*)alloc((size_t)4096 * 4);
  float* invd = (float*)alloc((size_t)4096 * 4);
  bf16_t* agg256 = (bf16_t*)alloc((size_t)256 * 512 * 2);
  bf16_t* s0f = (bf16_t*)alloc((size_t)256 * 512 * 2);
  bf16_t* tmpb = (bf16_t*)alloc((size_t)M_CAT * 512 * 2);
  bf16_t* h1 = (bf16_t*)alloc((size_t)M_CAT * 512 * 2);
  bf16_t* h2 = (bf16_t*)alloc((size_t)M_CAT * 512 * 2);
  bf16_t* qkb = (bf16_t*)alloc((size_t)M_CAT * 1024 * 2);
  bf16_t* vt = (bf16_t*)alloc((size_t)512 * M_CAT * 2);
  bf16_t* attno = (bf16_t*)alloc((size_t)M_CAT * 512 * 2);
  bf16_t* f1o = (bf16_t*)alloc((size_t)M_CAT * 1024 * 2);
  bf16_t* Ofb = (bf16_t*)alloc((size_t)NSPLIT * 4096 * 512 * 2);
  float* Ml = (float*)alloc((size_t)NSPLIT * 4 * 4096 * 2 * 4);
  int* cnt = (int*)alloc(1024);
  int* c0 = cnt;        // 68 entries (sage+LN, M_CAT)
  int* c1 = cnt + 68;   // 68 entries (outproj+LN, M_CAT)
  int* c2 = cnt + 136;  // 4 entries (layer1 sage+LN)
  int* c3 = cnt + 140;  // 4 entries (layer1 outproj+LN)

  hipMemsetAsync(cnt, 0, 576, stream);

  // weight + feature conversion; feats1 -> fcat rows 0..4096, feats0 -> tail
  cvt_all<<<6336, 256, 0, stream>>>(emb_w, sage_w, qkv_w, out_w, ffn_w1,
                                    ffn_w2, feats0, feats1, wemb, wsage, wqkv,
                                    wout, wf1, wf2, fcat + (size_t)4096 * 256,
                                    fcat);

  // depth-2 masked feature aggregation
  agg_feats<<<1024, 256, 0, stream>>>(feats2, nbmask1, nmask2, aggFb, swv, invd);
  // merged embedding: rows 0..4352 -> s_cat; rows 4352..8448 -> agg_cat[0..4096]
  mgemm<64, 64, 6, false><<<dim3((M_CAT + M_BIG) / 64, 8), 256, 0, stream>>>(
      fcat, aggFb, wemb, emb_b, nullptr, nmask1, nmask0, swv, invd, s_cat,
      nullptr, M_CAT + M_BIG, M_BIG, 512, 256, nullptr, nullptr);
  // depth-0 aggregation of OLD s1 (agg_cat rows 4096..4352)
  agg_state<<<64, 256, 0, stream>>>(s_cat, nbmask0,
                                    agg_cat + (size_t)M_BIG * 512);

  // ---- layer 0, fused depth-1 (4096 rows) + depth-0 (256 rows) ----
  mgemm<64, 64, 7, true><<<dim3(M_CAT / 64, 8), 256, 0, stream>>>(
      s_cat, agg_cat, wsage, sage_b, s_cat, n1_g, n1_b, nullptr, nullptr,
      tmpb, nullptr, M_CAT, 0, 512, 1024, h1, c0);
  mgemm<64, 64, 5, false><<<dim3(M_CAT / 64, 24), 256, 0, stream>>>(
      h1, nullptr, wqkv, qkv_b, nullptr, nullptr, nullptr, nullptr, nullptr,
      qkb, vt, M_CAT, 0, 1536, 512, nullptr, nullptr);
  // unified flash: 256 big blocks (4096 rows, SPLITS=4) + 4 tail blocks (256)
  flashT<8, 2, NSPLIT><<<(M_BIG / 256) * 4 * NSPLIT + 4, 512, 0, stream>>>(
      qkb, vt, nullptr, Ofb, Ml, M_BIG, M_CAT, qkb + (size_t)M_BIG * 1024,
      vt + M_BIG, attno + (size_t)M_BIG * 512, (M_BIG / 256) * 4 * NSPLIT, 256);
  merge_attn<NSPLIT><<<M_BIG, 256, 0, stream>>>(Ofb, Ml, attno, M_BIG);
  mgemm<64, 64, 7, false><<<dim3(M_CAT / 64, 8), 256, 0, stream>>>(
      attno, nullptr, wout, out_b, h1, n2_g, n2_b, nullptr, nullptr,
      tmpb, nullptr, M_CAT, 0, 512, 512, h2, c1);
  mgemm<64, 64, 3, false><<<dim3(M_CAT / 64, 16), 256, 0, stream>>>(
      h2, nullptr, wf1, ffn_b1, nullptr, nullptr, nullptr, nullptr, nullptr,
      f1o, nullptr, M_CAT, 0, 1024, 512, nullptr, nullptr);
  mgemm<64, 64, 4, false><<<dim3(M_CAT / 64, 8), 256, 0, stream>>>(
      f1o, nullptr, wf2, ffn_b2, h2, nmask1, nmask0, nullptr, nullptr, scat_o,
      nullptr, M_CAT, M_BIG, 512, 1024, nullptr, nullptr);

  // ---- layer 1, depth 0 (n=256): sf = scat_o rows 4096.., children = rows 0..4096
  const bf16_t* s1b = scat_o;
  const bf16_t* s0b = scat_o + (size_t)M_BIG * 512;
  agg_state<<<64, 256, 0, stream>>>(s1b, nbmask0, agg256);
  const bf16_t* wsage1 = wsage + 512 * 1024;
  const bf16_t* wqkv1 = wqkv + 1536 * 512;
  const bf16_t* wout1 = wout + 512 * 512;
  const bf16_t* wf11 = wf1 + 1024 * 512;
  const bf16_t* wf21 = wf2 + 512 * 1024;
  mgemm<64, 64, 7, true><<<dim3(4, 8), 256, 0, stream>>>(
      s0b, agg256, wsage1, sage_b + 512, s0b, n1_g + 512, n1_b + 512, nullptr,
      nullptr, tmpb, nullptr, 256, 0, 512, 1024, h1, c2);
  mgemm<64, 64, 5, false><<<dim3(4, 24), 256, 0, stream>>>(
      h1, nullptr, wqkv1, qkv_b + 1536, nullptr, nullptr, nullptr, nullptr,
      nullptr, qkb, vt, 256, 0, 1536, 512, nullptr, nullptr);
  flashT<4, 1, 1><<<(256 / 64) * 4, 256, 0, stream>>>(
      qkb, vt, attno, nullptr, nullptr, 256, 256, nullptr, nullptr, nullptr,
      (256 / 64) * 4, 0);
  mgemm<64, 64, 7, false><<<dim3(4, 8), 256, 0, stream>>>(
      attno, nullptr, wout1, out_b + 512, h1, n2_g + 512, n2_b + 512, nullptr,
      nullptr, tmpb, nullptr, 256, 0, 512, 512, h2, c3);
  mgemm<64, 64, 3, false><<<dim3(4, 16), 256, 0, stream>>>(
      h2, nullptr, wf11, ffn_b1 + 1024, nullptr, nullptr, nullptr, nullptr,
      nullptr, f1o, nullptr, 256, 0, 1024, 512, nullptr, nullptr);
  mgemm<64, 64, 4, false><<<dim3(4, 8), 256, 0, stream>>>(
      f1o, nullptr, wf21, ffn_b2 + 512, h2, nmask0, nmask0, nullptr, nullptr,
      s0f, nullptr, 256, 256, 512, 1024, nullptr, nullptr);

  cls_k<<<256, 256, 0, stream>>>(s0f, cls_w, cls_b, out);
}

// Round 14
// 266.985 us; speedup vs baseline: 1.7075x; 1.7075x over previous
//
#include <hip/hip_runtime.h>
#include <math.h>

// ---------------------------------------------------------------------------
// GraphTransformer, bf16 MFMA. Round 14: revert round-13's fence-based LN
// fusion (device-scope threadfence per block = L2 writeback storm, 106us/GEMM
// at 1.6% MfmaUtil). Back to round-12 structure (260.9us) + keep only the
// unified flash dispatch (big + tail blocks).
// NL=2, H=4, C=512, IN=256, F=16, B=256, NC=47, DH=128
// ---------------------------------------------------------------------------

typedef unsigned short bf16_t;
typedef __attribute__((ext_vector_type(8))) short bf16x8_t;
typedef __attribute__((ext_vector_type(4))) float f32x4_t;

#define M_BIG 4096
#define M_CAT 4352  // 4096 + 256
#define NSPLIT 4

__device__ __forceinline__ bf16_t f2bf(float f) {
  union { float f; unsigned u; } v; v.f = f;
  unsigned r = v.u + 0x7FFFu + ((v.u >> 16) & 1u);
  return (bf16_t)(r >> 16);
}
__device__ __forceinline__ float bf2f(bf16_t u) {
  union { unsigned u; float f; } v; v.u = ((unsigned)u) << 16; return v.f;
}
__device__ __forceinline__ unsigned cvtpk(float lo, float hi) {
  unsigned r;
  asm("v_cvt_pk_bf16_f32 %0, %1, %2" : "=v"(r) : "v"(lo), "v"(hi));
  return r;
}
__device__ __forceinline__ void gload16(const void* g, void* l) {
  __builtin_amdgcn_global_load_lds(
      (const __attribute__((address_space(1))) unsigned int*)g,
      (__attribute__((address_space(3))) unsigned int*)l, 16, 0, 0);
}

// Q pre-scale: 1/sqrt(128) * log2(e)  (softmax runs in log2 domain)
#define QSCALE (0.08838834764831845f * 1.4426950408889634f)

// ---------------------------------------------------------------------------
// GEMM: C[M,N] = A[M,K] @ W[N,K]^T + epilogue. A,W bf16; accum fp32.
// MODE 0: Cb = acc + b
// MODE 3: Cb = relu(acc + b)                    (ffn1)
// MODE 4: Cb = (acc + b + res[m,n]) * (m<M1?rowa:rowa2)  (ffn2+resid+nmask)
// MODE 5: qkv: n<512 -> Cb[m,1024]*QSCALE; <1024 -> Cb; >=1024 -> Vt[n-1024,m]
// MODE 6: merged embedding (rows 0..M_CAT = fcat -> nmask1|nmask0;
//         rows M_CAT.. = aggFb -> (acc + b*rowb)*rowc)
// ---------------------------------------------------------------------------
template <int BM, int BN, int MODE, bool SPLIT>
__global__ __launch_bounds__(256) void mgemm(
    const bf16_t* __restrict__ A, const bf16_t* __restrict__ A2,
    const bf16_t* __restrict__ W, const float* __restrict__ bias,
    const bf16_t* __restrict__ res, const float* __restrict__ rowa,
    const float* __restrict__ rowa2, const float* __restrict__ rowb,
    const float* __restrict__ rowc,
    bf16_t* __restrict__ Cb, bf16_t* __restrict__ Vt,
    int M, int M1, int N, int K) {
  constexpr int FM = BM / 32, FN = BN / 32;
  constexpr int NCH = (BM + BN) / 16;
  constexpr int CPW = NCH / 4;
  __shared__ bf16_t lds[2][(BM + BN) * 32];
  const int t = threadIdx.x;
  const int w = t >> 6, lane = t & 63;
  const int g = lane >> 4, li = lane & 15;
  const int bm = blockIdx.x * BM, bn = blockIdx.y * BN;
  const int wr = (w >> 1) * (BM / 2), wc = (w & 1) * (BN / 2);
  f32x4_t acc[FM][FN] = {};

  auto stage = [&](int buf, int k0) {
#pragma unroll
    for (int c0 = 0; c0 < CPW; ++c0) {
      const int c = w * CPW + c0;
      const int row = c * 16 + (lane >> 2);
      const int gk = k0 + (lane & 3) * 8;
      const bf16_t* src;
      if (row < BM) {
        const int grow = bm + row;
        if (MODE == 6) {
          src = (grow < M_CAT) ? (A + (size_t)grow * K + gk)
                               : (A2 + (size_t)(grow - M_CAT) * K + gk);
        } else if (SPLIT) {
          src = (gk < 512) ? (A + (size_t)grow * 512 + gk)
                           : (A2 + (size_t)grow * 512 + (gk - 512));
        } else {
          src = A + (size_t)grow * K + gk;
        }
      } else {
        src = W + (size_t)(bn + row - BM) * K + gk;
      }
      gload16(src, &lds[buf][c * 512]);
    }
  };

  const int nk = K / 32;
  stage(0, 0);
  for (int ks = 0; ks < nk; ++ks) {
    __syncthreads();
    if (ks + 1 < nk) stage((ks + 1) & 1, (ks + 1) * 32);
    const bf16_t* As = &lds[ks & 1][0];
    const bf16_t* Bs = &lds[ks & 1][BM * 32];
    bf16x8_t af[FM], bfr[FN];
#pragma unroll
    for (int i = 0; i < FM; ++i)
      af[i] = *(const bf16x8_t*)(As + (wr + i * 16 + li) * 32 + g * 8);
#pragma unroll
    for (int j = 0; j < FN; ++j)
      bfr[j] = *(const bf16x8_t*)(Bs + (wc + j * 16 + li) * 32 + g * 8);
#pragma unroll
    for (int i = 0; i < FM; ++i)
#pragma unroll
      for (int j = 0; j < FN; ++j)
        acc[i][j] = __builtin_amdgcn_mfma_f32_16x16x32_bf16(
            af[i], bfr[j], acc[i][j], 0, 0, 0);
  }

  // epilogue: D frag: col n = li, row m = g*4 + reg (verified layout)
#pragma unroll
  for (int i = 0; i < FM; ++i) {
    const int mb = bm + wr + i * 16 + g * 4;
#pragma unroll
    for (int j = 0; j < FN; ++j) {
      const int n = bn + wc + j * 16 + li;
      if (MODE == 5) {
        const float bb = bias[n];
        if (n < 512) {
#pragma unroll
          for (int r = 0; r < 4; ++r)
            Cb[(size_t)(mb + r) * 1024 + n] = f2bf((acc[i][j][r] + bb) * QSCALE);
        } else if (n < 1024) {
#pragma unroll
          for (int r = 0; r < 4; ++r)
            Cb[(size_t)(mb + r) * 1024 + n] = f2bf(acc[i][j][r] + bb);
        } else {
          ushort4 o;
          o.x = f2bf(acc[i][j][0] + bb); o.y = f2bf(acc[i][j][1] + bb);
          o.z = f2bf(acc[i][j][2] + bb); o.w = f2bf(acc[i][j][3] + bb);
          *(ushort4*)(Vt + (size_t)(n - 1024) * M + mb) = o;
        }
      } else {
#pragma unroll
        for (int r = 0; r < 4; ++r) {
          const int m = mb + r;
          const float v = acc[i][j][r];
          if (MODE == 0) Cb[(size_t)m * N + n] = f2bf(v + bias[n]);
          if (MODE == 3) Cb[(size_t)m * N + n] = f2bf(fmaxf(v + bias[n], 0.f));
          if (MODE == 4) {
            const float ra = (m < M1) ? rowa[m] : rowa2[m - M1];
            Cb[(size_t)m * N + n] =
                f2bf((v + bias[n] + bf2f(res[(size_t)m * N + n])) * ra);
          }
          if (MODE == 6) {
            float val;
            if (m < M1) val = (v + bias[n]) * rowa[m];
            else if (m < M_CAT) val = (v + bias[n]) * rowa2[m - M1];
            else {
              const int mm = m - M_CAT;
              val = (v + bias[n] * rowb[mm]) * rowc[mm];
            }
            Cb[(size_t)m * N + n] = f2bf(val);
          }
        }
      }
    }
  }
}

// ---------------------------------------------------------------------------
// Flash attention, swapped-operand, double-buffered. NW waves; NQC q-frags
// per wave; two-pass PV (80KB LDS). Blocks >= nbig run the "tail" problem
// (qk2/vt2, N2 keys, direct write to attno2).
// ---------------------------------------------------------------------------
template <int NW, int NQC, int SPLITS>
__global__ __launch_bounds__(NW * 64) void flashT(
    const bf16_t* __restrict__ qk, const bf16_t* __restrict__ vt,
    bf16_t* __restrict__ attno, bf16_t* __restrict__ Ofb,
    float* __restrict__ Ml, int N, int VS,
    const bf16_t* __restrict__ qk2, const bf16_t* __restrict__ vt2,
    bf16_t* __restrict__ attno2, int nbig, int N2) {
  constexpr int QB = NW * NQC * 16;  // q rows per block
  constexpr int KCH = 16 / NW;       // staging chunks per wave (K and V each)
  __shared__ bf16_t Ks[2][64 * 128];
  __shared__ bf16_t Vs[2][128 * 64];
  __shared__ bf16_t Ps[NW][16 * 64];
  const int bid = blockIdx.x;
  int sp, h, qb, kvbase, nt;
  bool direct;
  const bf16_t *qkB, *vtB;
  bf16_t* attD;
  if (bid < nbig) {
    sp = bid % SPLITS;
    h = (bid / SPLITS) & 3;
    qb = bid / (4 * SPLITS);
    qkB = qk; vtB = vt;
    kvbase = sp * (N / SPLITS);
    nt = (N / SPLITS) >> 6;
    direct = (SPLITS == 1);
    attD = attno;
  } else {
    const int b2 = bid - nbig;
    sp = 0; h = b2 & 3; qb = 0;
    qkB = qk2; vtB = vt2;
    kvbase = 0;
    nt = N2 >> 6;
    direct = true;
    attD = attno2;
  }
  const int t = threadIdx.x, w = t >> 6, lane = t & 63;
  const int g = lane >> 4, li = lane & 15;

  bf16x8_t qf[NQC][4];
#pragma unroll
  for (int qc = 0; qc < NQC; ++qc) {
    const bf16_t* qrow =
        qkB + (size_t)(qb * QB + w * (NQC * 16) + qc * 16 + li) * 1024 + h * 128;
#pragma unroll
    for (int ks = 0; ks < 4; ++ks)
      qf[qc][ks] = *(const bf16x8_t*)(qrow + ks * 32 + g * 8);
  }

  // hoisted LDS byte offsets (xor-swizzled layout, round-2-verified)
  int koff[4], voff[2], pwoff[4];
#pragma unroll
  for (int ks = 0; ks < 4; ++ks)
    koff[ks] = li * 256 + (((ks * 4 + g) ^ (li & 7)) << 4);
#pragma unroll
  for (int ks = 0; ks < 2; ++ks)
    voff[ks] = li * 128 + (((ks * 4 + g) ^ (li & 7)) << 4);
#pragma unroll
  for (int mf = 0; mf < 4; ++mf)
    pwoff[mf] = li * 128 + (((mf * 2 + (g >> 1)) ^ (li & 7)) << 4) +
                ((g & 1) << 3);
  char* Pb = (char*)Ps + w * 2048;

  // running staging pointers (advance per tile)
  const bf16_t* kp[KCH];
  const bf16_t* vp[KCH];
#pragma unroll
  for (int i = 0; i < KCH; ++i) {
    const int c = w * KCH + i;
    const int rk = c * 4 + (lane >> 4);
    kp[i] = qkB + (size_t)(kvbase + rk) * 1024 + 512 + h * 128 +
            (((lane & 15) ^ (rk & 7)) * 8);
    const int rv = c * 8 + (lane >> 3);
    vp[i] = vtB + (size_t)(h * 128 + rv) * VS + kvbase +
            (((lane & 7) ^ (rv & 7)) * 8);
  }
  auto stage = [&](int buf) {
#pragma unroll
    for (int i = 0; i < KCH; ++i) {
      const int c = w * KCH + i;
      gload16(kp[i], &Ks[buf][c * 512]);
      kp[i] += (size_t)64 * 1024;
      gload16(vp[i], &Vs[buf][c * 512]);
      vp[i] += 64;
    }
  };

  f32x4_t acc[NQC][8] = {};
  float mrun[NQC], lrun[NQC];
#pragma unroll
  for (int qc = 0; qc < NQC; ++qc) { mrun[qc] = -1e30f; lrun[qc] = 0.f; }

  stage(0);
  for (int tt = 0; tt < nt; ++tt) {
    const int cur = tt & 1;
    __syncthreads();  // drains own stage loads (vmcnt(0)) -> cur resident
    if (tt + 1 < nt) stage(cur ^ 1);  // prefetch overlaps with compute below
    const char* Kb = (const char*)Ks + cur * 16384;
    const char* Vb = (const char*)Vs + cur * 16384;

    // S^T = K · Q^T : frag row kv = mf*16+g*4+r, col q = li (per qc)
    f32x4_t sf[NQC][4];
#pragma unroll
    for (int qc = 0; qc < NQC; ++qc)
#pragma unroll
      for (int mf = 0; mf < 4; ++mf) sf[qc][mf] = (f32x4_t){0.f, 0.f, 0.f, 0.f};
    __builtin_amdgcn_s_setprio(1);
#pragma unroll
    for (int ks = 0; ks < 4; ++ks) {
#pragma unroll
      for (int mf = 0; mf < 4; ++mf) {
        const bf16x8_t kf = *(const bf16x8_t*)(Kb + koff[ks] + mf * 4096);
#pragma unroll
        for (int qc = 0; qc < NQC; ++qc)
          sf[qc][mf] = __builtin_amdgcn_mfma_f32_16x16x32_bf16(
              kf, qf[qc][ks], sf[qc][mf], 0, 0, 0);
      }
    }
    __builtin_amdgcn_s_setprio(0);

    // online softmax (log2 domain); lane li owns q-rows (qc*16+li)
    float tmax[NQC];
#pragma unroll
    for (int qc = 0; qc < NQC; ++qc) {
      float tm = -1e30f;
#pragma unroll
      for (int mf = 0; mf < 4; ++mf)
#pragma unroll
        for (int r = 0; r < 4; ++r) tm = fmaxf(tm, sf[qc][mf][r]);
      tm = fmaxf(tm, __shfl_xor(tm, 16));
      tm = fmaxf(tm, __shfl_xor(tm, 32));
      tmax[qc] = tm;
    }
    float worst = tmax[0] - mrun[0];
#pragma unroll
    for (int qc = 1; qc < NQC; ++qc)
      worst = fmaxf(worst, tmax[qc] - mrun[qc]);
    if (!__all(worst <= 11.0f)) {  // defer-rescale (P bounded by 2^11)
#pragma unroll
      for (int qc = 0; qc < NQC; ++qc) {
        const float mnew = fmaxf(mrun[qc], tmax[qc]);
        const float fsc = exp2f(mrun[qc] - mnew);
        mrun[qc] = mnew;
        lrun[qc] *= fsc;
#pragma unroll
        for (int mf = 0; mf < 8; ++mf) acc[qc][mf] *= fsc;
      }
    }
#pragma unroll
    for (int qc = 0; qc < NQC; ++qc) {
      float lsum = 0.f;
#pragma unroll
      for (int mf = 0; mf < 4; ++mf)
#pragma unroll
        for (int r = 0; r < 4; ++r) {
          const float p = exp2f(sf[qc][mf][r] - mrun[qc]);
          sf[qc][mf][r] = p;
          lsum += p;
        }
      lsum += __shfl_xor(lsum, 16);
      lsum += __shfl_xor(lsum, 32);
      lrun[qc] += lsum;
    }

    // PV, one pass per qc: P -> per-wave LDS, then O^T += Vt · P^T.
    __builtin_amdgcn_s_setprio(1);
#pragma unroll
    for (int qc = 0; qc < NQC; ++qc) {
#pragma unroll
      for (int mf = 0; mf < 4; ++mf) {
        uint2 pv;
        pv.x = cvtpk(sf[qc][mf][0], sf[qc][mf][1]);
        pv.y = cvtpk(sf[qc][mf][2], sf[qc][mf][3]);
        *(uint2*)(Pb + pwoff[mf]) = pv;
      }
#pragma unroll
      for (int ks = 0; ks < 2; ++ks) {
        const bf16x8_t pf = *(const bf16x8_t*)(Pb + voff[ks]);
#pragma unroll
        for (int mf = 0; mf < 8; ++mf) {
          const bf16x8_t vf = *(const bf16x8_t*)(Vb + voff[ks] + mf * 2048);
          acc[qc][mf] = __builtin_amdgcn_mfma_f32_16x16x32_bf16(
              vf, pf, acc[qc][mf], 0, 0, 0);
        }
      }
    }
    __builtin_amdgcn_s_setprio(0);
  }

#pragma unroll
  for (int qc = 0; qc < NQC; ++qc) {
    const float invl = 1.f / lrun[qc];
    const int q = qb * QB + w * (NQC * 16) + qc * 16 + li;
    bf16_t* dst = direct ? (attD + (size_t)q * 512 + h * 128)
                         : (Ofb + ((size_t)sp * N + q) * 512 + h * 128);
#pragma unroll
    for (int mf = 0; mf < 8; ++mf) {
      ushort4 o;
      o.x = f2bf(acc[qc][mf][0] * invl); o.y = f2bf(acc[qc][mf][1] * invl);
      o.z = f2bf(acc[qc][mf][2] * invl); o.w = f2bf(acc[qc][mf][3] * invl);
      *(ushort4*)(dst + mf * 16 + g * 4) = o;
    }
    if (!direct && lane < 16) {
      float2 ml; ml.x = mrun[qc]; ml.y = lrun[qc];
      *(float2*)(Ml + ((size_t)(sp * 4 + h) * N + q) * 2) = ml;
    }
  }
}

// merge SPLITS normalized partials: w_s = l_s * 2^(m_s - m); out = Σ w_s O_s / Σ w_s
template <int SPLITS>
__global__ __launch_bounds__(256) void merge_attn(
    const bf16_t* __restrict__ Ofb, const float* __restrict__ Ml,
    bf16_t* __restrict__ attno, int N) {
  const int q = blockIdx.x, t = threadIdx.x;
#pragma unroll
  for (int half = 0; half < 2; ++half) {
    const int c = t + half * 256;
    const int h = c >> 7;
    float2 ml[SPLITS];
    float m = -1e30f;
#pragma unroll
    for (int s = 0; s < SPLITS; ++s) {
      ml[s] = ((const float2*)Ml)[(s * 4 + h) * N + q];
      m = fmaxf(m, ml[s].x);
    }
    float num = 0.f, den = 0.f;
#pragma unroll
    for (int s = 0; s < SPLITS; ++s) {
      const float wgt = ml[s].y * exp2f(ml[s].x - m);
      num += bf2f(Ofb[((size_t)s * N + q) * 512 + c]) * wgt;
      den += wgt;
    }
    attno[(size_t)q * 512 + c] = f2bf(num / den);
  }
}

// ---------------------------------------------------------------------------
__global__ __launch_bounds__(256) void add_ln(
    const bf16_t* __restrict__ X, const bf16_t* __restrict__ Y,
    const float* __restrict__ gg, const float* __restrict__ bb,
    bf16_t* __restrict__ out) {
  const int row = blockIdx.x, t = threadIdx.x;
  const size_t base = (size_t)row * 512;
  const float x0 = bf2f(X[base + t]) + bf2f(Y[base + t]);
  const float x1 = bf2f(X[base + 256 + t]) + bf2f(Y[base + 256 + t]);
  float s = x0 + x1, ss = x0 * x0 + x1 * x1;
#pragma unroll
  for (int o = 32; o > 0; o >>= 1) {
    s += __shfl_down(s, o);
    ss += __shfl_down(ss, o);
  }
  __shared__ float rs[4], rss[4], sm[2];
  const int wv = t >> 6, ln = t & 63;
  if (ln == 0) { rs[wv] = s; rss[wv] = ss; }
  __syncthreads();
  if (t == 0) {
    const float S = rs[0] + rs[1] + rs[2] + rs[3];
    const float SS = rss[0] + rss[1] + rss[2] + rss[3];
    const float mean = S * (1.f / 512.f);
    sm[0] = mean;
    sm[1] = rsqrtf(SS * (1.f / 512.f) - mean * mean + 1e-5f);
  }
  __syncthreads();
  const float mean = sm[0], rstd = sm[1];
  out[base + t] = f2bf((x0 - mean) * rstd * gg[t] + bb[t]);
  out[base + 256 + t] = f2bf((x1 - mean) * rstd * gg[t + 256] + bb[t + 256]);
}

// vectorized: 4 nodes per block, 64 lanes x float4 per node
__global__ __launch_bounds__(256) void agg_feats(
    const float* __restrict__ feats2, const int* __restrict__ nbm,
    const float* __restrict__ nm2, bf16_t* __restrict__ aggF,
    float* __restrict__ sw, float* __restrict__ invd) {
  const int node = blockIdx.x * 4 + (threadIdx.x >> 6);
  const int lane = threadIdx.x & 63;
  float4 acc = {0.f, 0.f, 0.f, 0.f};
  float ws = 0.f, nbs = 0.f;
#pragma unroll
  for (int j = 0; j < 16; ++j) {
    const float nb = (float)nbm[node * 16 + j];
    const float wj = nb * nm2[node * 16 + j];
    const float4 v =
        *(const float4*)(feats2 + (size_t)(node * 16 + j) * 256 + lane * 4);
    acc.x += wj * v.x; acc.y += wj * v.y;
    acc.z += wj * v.z; acc.w += wj * v.w;
    ws += wj;
    nbs += nb;
  }
  ushort4 o;
  o.x = f2bf(acc.x); o.y = f2bf(acc.y); o.z = f2bf(acc.z); o.w = f2bf(acc.w);
  *(ushort4*)(aggF + (size_t)node * 256 + lane * 4) = o;
  if (lane == 0) { sw[node] = ws; invd[node] = 1.f / fmaxf(nbs, 1.f); }
}

// vectorized: 4 nodes per block (one per wave), lane covers 8 cols (bf16x8)
__global__ __launch_bounds__(256) void agg_state(
    const bf16_t* __restrict__ src, const int* __restrict__ nbm,
    bf16_t* __restrict__ agg) {
  const int node = blockIdx.x * 4 + (threadIdx.x >> 6);
  const int lane = threadIdx.x & 63;
  float acc[8] = {};
  float nbs = 0.f;
#pragma unroll
  for (int j = 0; j < 16; ++j) {
    const float nb = (float)nbm[node * 16 + j];
    nbs += nb;
    const bf16x8_t v =
        *(const bf16x8_t*)(src + (size_t)(node * 16 + j) * 512 + lane * 8);
#pragma unroll
    for (int e = 0; e < 8; ++e) acc[e] += nb * bf2f((bf16_t)v[e]);
  }
  const float inv = 1.f / fmaxf(nbs, 1.f);
  bf16x8_t o;
#pragma unroll
  for (int e = 0; e < 8; ++e) o[e] = (short)f2bf(acc[e] * inv);
  *(bf16x8_t*)(agg + (size_t)node * 512 + lane * 8) = o;
}

// all fp32->bf16 conversions in one dispatch (float4-unit segments)
__global__ __launch_bounds__(256) void cvt_all(
    const float* __restrict__ s_emb, const float* __restrict__ s_sage,
    const float* __restrict__ s_qkv, const float* __restrict__ s_out,
    const float* __restrict__ s_f1, const float* __restrict__ s_f2,
    const float* __restrict__ s_ft0, const float* __restrict__ s_ft1,
    bf16_t* __restrict__ d_emb, bf16_t* __restrict__ d_sage,
    bf16_t* __restrict__ d_qkv, bf16_t* __restrict__ d_out,
    bf16_t* __restrict__ d_f1, bf16_t* __restrict__ d_f2,
    bf16_t* __restrict__ d_ft0, bf16_t* __restrict__ d_ft1) {
  int i = blockIdx.x * 256 + threadIdx.x;
  const float* s; bf16_t* d; int base;
  if (i < 32768)        { s = s_emb;  d = d_emb;  base = 0; }
  else if (i < 294912)  { s = s_sage; d = d_sage; base = 32768; }
  else if (i < 688128)  { s = s_qkv;  d = d_qkv;  base = 294912; }
  else if (i < 819200)  { s = s_out;  d = d_out;  base = 688128; }
  else if (i < 1081344) { s = s_f1;   d = d_f1;   base = 819200; }
  else if (i < 1343488) { s = s_f2;   d = d_f2;   base = 1081344; }
  else if (i < 1359872) { s = s_ft0;  d = d_ft0;  base = 1343488; }
  else                  { s = s_ft1;  d = d_ft1;  base = 1359872; }
  i -= base;
  const float4 v = ((const float4*)s)[i];
  ushort4 o;
  o.x = f2bf(v.x); o.y = f2bf(v.y); o.z = f2bf(v.z); o.w = f2bf(v.w);
  ((ushort4*)d)[i] = o;
}

__global__ __launch_bounds__(256) void cls_k(
    const bf16_t* __restrict__ s, const float* __restrict__ wc,
    const float* __restrict__ bc, float* __restrict__ out) {
  __shared__ float srow[512];
  const int m = blockIdx.x, t = threadIdx.x;
  srow[t] = bf2f(s[(size_t)m * 512 + t]);
  srow[t + 256] = bf2f(s[(size_t)m * 512 + 256 + t]);
  __syncthreads();
  if (t < 47) {
    float a = bc[t];
    const float* wr = wc + (size_t)t * 512;
    for (int k = 0; k < 512; ++k) a += srow[k] * wr[k];
    out[(size_t)m * 47 + t] = a;
  }
}

// ---------------------------------------------------------------------------
extern "C" void kernel_launch(void* const* d_in, const int* in_sizes, int n_in,
                              void* d_out, int out_size, void* d_ws,
                              size_t ws_size, hipStream_t stream) {
  const float* feats0 = (const float*)d_in[0];
  const float* feats1 = (const float*)d_in[1];
  const float* feats2 = (const float*)d_in[2];
  const float* nmask0 = (const float*)d_in[3];
  const float* nmask1 = (const float*)d_in[4];
  const float* nmask2 = (const float*)d_in[5];
  const int* nbmask0 = (const int*)d_in[6];
  const int* nbmask1 = (const int*)d_in[7];
  const float* emb_w = (const float*)d_in[8];
  const float* emb_b = (const float*)d_in[9];
  const float* sage_w = (const float*)d_in[10];
  const float* sage_b = (const float*)d_in[11];
  const float* qkv_w = (const float*)d_in[12];
  const float* qkv_b = (const float*)d_in[13];
  const float* out_w = (const float*)d_in[14];
  const float* out_b = (const float*)d_in[15];
  const float* n1_g = (const float*)d_in[16];
  const float* n1_b = (const float*)d_in[17];
  const float* n2_g = (const float*)d_in[18];
  const float* n2_b = (const float*)d_in[19];
  const float* ffn_w1 = (const float*)d_in[20];
  const float* ffn_b1 = (const float*)d_in[21];
  const float* ffn_w2 = (const float*)d_in[22];
  const float* ffn_b2 = (const float*)d_in[23];
  const float* cls_w = (const float*)d_in[24];
  const float* cls_b = (const float*)d_in[25];
  float* out = (float*)d_out;

  size_t off = 0;
  auto alloc = [&](size_t bytes) {
    void* r = (char*)d_ws + off;
    off += (bytes + 255) & ~(size_t)255;
    return r;
  };
  bf16_t* wemb = (bf16_t*)alloc((size_t)512 * 256 * 2);
  bf16_t* wsage = (bf16_t*)alloc((size_t)2 * 512 * 1024 * 2);
  bf16_t* wqkv = (bf16_t*)alloc((size_t)2 * 1536 * 512 * 2);
  bf16_t* wout = (bf16_t*)alloc((size_t)2 * 512 * 512 * 2);
  bf16_t* wf1 = (bf16_t*)alloc((size_t)2 * 1024 * 512 * 2);
  bf16_t* wf2 = (bf16_t*)alloc((size_t)2 * 512 * 1024 * 2);
  bf16_t* fcat = (bf16_t*)alloc((size_t)M_CAT * 256 * 2);   // feats1|feats0
  bf16_t* s_cat = (bf16_t*)alloc((size_t)2 * M_CAT * 512 * 2);
  bf16_t* agg_cat = s_cat + (size_t)M_CAT * 512;
  bf16_t* scat_o = (bf16_t*)alloc((size_t)M_CAT * 512 * 2); // s1b|s0b
  bf16_t* aggFb = (bf16_t*)alloc((size_t)4096 * 256 * 2);
  float* swv = (float*)alloc((size_t)4096 * 4);
  float* invd = (float*)alloc((size_t)4096 * 4);
  bf16_t* agg256 = (bf16_t*)alloc((size_t)256 * 512 * 2);
  bf16_t* s0f = (bf16_t*)alloc((size_t)256 * 512 * 2);
  bf16_t* tmpb = (bf16_t*)alloc((size_t)M_CAT * 512 * 2);
  bf16_t* h1 = (bf16_t*)alloc((size_t)M_CAT * 512 * 2);
  bf16_t* h2 = (bf16_t*)alloc((size_t)M_CAT * 512 * 2);
  bf16_t* qkb = (bf16_t*)alloc((size_t)M_CAT * 1024 * 2);
  bf16_t* vt = (bf16_t*)alloc((size_t)512 * M_CAT * 2);
  bf16_t* attno = (bf16_t*)alloc((size_t)M_CAT * 512 * 2);
  bf16_t* f1o = (bf16_t*)alloc((size_t)M_CAT * 1024 * 2);
  bf16_t* Ofb = (bf16_t*)alloc((size_t)NSPLIT * 4096 * 512 * 2);
  float* Ml = (float*)alloc((size_t)NSPLIT * 4 * 4096 * 2 * 4);

  // weight + feature conversion; feats1 -> fcat rows 0..4096, feats0 -> tail
  cvt_all<<<6336, 256, 0, stream>>>(emb_w, sage_w, qkv_w, out_w, ffn_w1,
                                    ffn_w2, feats0, feats1, wemb, wsage, wqkv,
                                    wout, wf1, wf2, fcat + (size_t)4096 * 256,
                                    fcat);

  // depth-2 masked feature aggregation
  agg_feats<<<1024, 256, 0, stream>>>(feats2, nbmask1, nmask2, aggFb, swv, invd);
  // merged embedding: rows 0..4352 -> s_cat; rows 4352..8448 -> agg_cat[0..4096]
  mgemm<64, 64, 6, false><<<dim3((M_CAT + M_BIG) / 64, 8), 256, 0, stream>>>(
      fcat, aggFb, wemb, emb_b, nullptr, nmask1, nmask0, swv, invd, s_cat,
      nullptr, M_CAT + M_BIG, M_BIG, 512, 256);
  // depth-0 aggregation of OLD s1 (agg_cat rows 4096..4352)
  agg_state<<<64, 256, 0, stream>>>(s_cat, nbmask0,
                                    agg_cat + (size_t)M_BIG * 512);

  // ---- layer 0, fused depth-1 (4096 rows) + depth-0 (256 rows) ----
  mgemm<64, 64, 0, true><<<dim3(M_CAT / 64, 8), 256, 0, stream>>>(
      s_cat, agg_cat, wsage, sage_b, nullptr, nullptr, nullptr, nullptr,
      nullptr, tmpb, nullptr, M_CAT, 0, 512, 1024);
  add_ln<<<M_CAT, 256, 0, stream>>>(s_cat, tmpb, n1_g, n1_b, h1);
  mgemm<64, 64, 5, false><<<dim3(M_CAT / 64, 24), 256, 0, stream>>>(
      h1, nullptr, wqkv, qkv_b, nullptr, nullptr, nullptr, nullptr, nullptr,
      qkb, vt, M_CAT, 0, 1536, 512);
  // unified flash: 256 big blocks (4096 rows, SPLITS=4) + 4 tail blocks (256)
  flashT<8, 2, NSPLIT><<<(M_BIG / 256) * 4 * NSPLIT + 4, 512, 0, stream>>>(
      qkb, vt, nullptr, Ofb, Ml, M_BIG, M_CAT, qkb + (size_t)M_BIG * 1024,
      vt + M_BIG, attno + (size_t)M_BIG * 512, (M_BIG / 256) * 4 * NSPLIT, 256);
  merge_attn<NSPLIT><<<M_BIG, 256, 0, stream>>>(Ofb, Ml, attno, M_BIG);
  mgemm<64, 64, 0, false><<<dim3(M_CAT / 64, 8), 256, 0, stream>>>(
      attno, nullptr, wout, out_b, nullptr, nullptr, nullptr, nullptr, nullptr,
      tmpb, nullptr, M_CAT, 0, 512, 512);
  add_ln<<<M_CAT, 256, 0, stream>>>(h1, tmpb, n2_g, n2_b, h2);
  mgemm<64, 64, 3, false><<<dim3(M_CAT / 64, 16), 256, 0, stream>>>(
      h2, nullptr, wf1, ffn_b1, nullptr, nullptr, nullptr, nullptr, nullptr,
      f1o, nullptr, M_CAT, 0, 1024, 512);
  mgemm<64, 64, 4, false><<<dim3(M_CAT / 64, 8), 256, 0, stream>>>(
      f1o, nullptr, wf2, ffn_b2, h2, nmask1, nmask0, nullptr, nullptr, scat_o,
      nullptr, M_CAT, M_BIG, 512, 1024);

  // ---- layer 1, depth 0 (n=256): sf = scat_o rows 4096.., children = rows 0..4096
  const bf16_t* s1b = scat_o;
  const bf16_t* s0b = scat_o + (size_t)M_BIG * 512;
  agg_state<<<64, 256, 0, stream>>>(s1b, nbmask0, agg256);
  const bf16_t* wsage1 = wsage + 512 * 1024;
  const bf16_t* wqkv1 = wqkv + 1536 * 512;
  const bf16_t* wout1 = wout + 512 * 512;
  const bf16_t* wf11 = wf1 + 1024 * 512;
  const bf16_t* wf21 = wf2 + 512 * 1024;
  mgemm<64, 64, 0, true><<<dim3(4, 8), 256, 0, stream>>>(
      s0b, agg256, wsage1, sage_b + 512, nullptr, nullptr, nullptr, nullptr,
      nullptr, tmpb, nullptr, 256, 0, 512, 1024);
  add_ln<<<256, 256, 0, stream>>>(s0b, tmpb, n1_g + 512, n1_b + 512, h1);
  mgemm<64, 64, 5, false><<<dim3(4, 24), 256, 0, stream>>>(
      h1, nullptr, wqkv1, qkv_b + 1536, nullptr, nullptr, nullptr, nullptr,
      nullptr, qkb, vt, 256, 0, 1536, 512);
  flashT<4, 1, 1><<<(256 / 64) * 4, 256, 0, stream>>>(
      qkb, vt, attno, nullptr, nullptr, 256, 256, nullptr, nullptr, nullptr,
      (256 / 64) * 4, 0);
  mgemm<64, 64, 0, false><<<dim3(4, 8), 256, 0, stream>>>(
      attno, nullptr, wout1, out_b + 512, nullptr, nullptr, nullptr, nullptr,
      nullptr, tmpb, nullptr, 256, 0, 512, 512);
  add_ln<<<256, 256, 0, stream>>>(h1, tmpb, n2_g + 512, n2_b + 512, h2);
  mgemm<64, 64, 3, false><<<dim3(4, 16), 256, 0, stream>>>(
      h2, nullptr, wf11, ffn_b1 + 1024, nullptr, nullptr, nullptr, nullptr,
      nullptr, f1o, nullptr, 256, 0, 1024, 512);
  mgemm<64, 64, 4, false><<<dim3(4, 8), 256, 0, stream>>>(
      f1o, nullptr, wf21, ffn_b2 + 512, h2, nmask0, nmask0, nullptr, nullptr,
      s0f, nullptr, 256, 256, 512, 1024);

  cls_k<<<256, 256, 0, stream>>>(s0f, cls_w, cls_b, out);
}

// Round 15
// 266.723 us; speedup vs baseline: 1.7092x; 1.0010x over previous
//
#include <hip/hip_runtime.h>
#include <math.h>

// ---------------------------------------------------------------------------
// GraphTransformer, bf16 MFMA. Round 14: revert round-13's fence-based LN
// fusion (device-scope threadfence per block = L2 writeback storm, 106us/GEMM
// at 1.6% MfmaUtil). Back to round-12 structure (260.9us) + keep only the
// unified flash dispatch (big + tail blocks).
// NL=2, H=4, C=512, IN=256, F=16, B=256, NC=47, DH=128
// ---------------------------------------------------------------------------

typedef unsigned short bf16_t;
typedef __attribute__((ext_vector_type(8))) short bf16x8_t;
typedef __attribute__((ext_vector_type(4))) float f32x4_t;

#define M_BIG 4096
#define M_CAT 4352  // 4096 + 256
#define NSPLIT 4

__device__ __forceinline__ bf16_t f2bf(float f) {
  union { float f; unsigned u; } v; v.f = f;
  unsigned r = v.u + 0x7FFFu + ((v.u >> 16) & 1u);
  return (bf16_t)(r >> 16);
}
__device__ __forceinline__ float bf2f(bf16_t u) {
  union { unsigned u; float f; } v; v.u = ((unsigned)u) << 16; return v.f;
}
__device__ __forceinline__ unsigned cvtpk(float lo, float hi) {
  unsigned r;
  asm("v_cvt_pk_bf16_f32 %0, %1, %2" : "=v"(r) : "v"(lo), "v"(hi));
  return r;
}
__device__ __forceinline__ void gload16(const void* g, void* l) {
  __builtin_amdgcn_global_load_lds(
      (const __attribute__((address_space(1))) unsigned int*)g,
      (__attribute__((address_space(3))) unsigned int*)l, 16, 0, 0);
}

// Q pre-scale: 1/sqrt(128) * log2(e)  (softmax runs in log2 domain)
#define QSCALE (0.08838834764831845f * 1.4426950408889634f)

// ---------------------------------------------------------------------------
// GEMM: C[M,N] = A[M,K] @ W[N,K]^T + epilogue. A,W bf16; accum fp32.
// MODE 0: Cb = acc + b
// MODE 3: Cb = relu(acc + b)                    (ffn1)
// MODE 4: Cb = (acc + b + res[m,n]) * (m<M1?rowa:rowa2)  (ffn2+resid+nmask)
// MODE 5: qkv: n<512 -> Cb[m,1024]*QSCALE; <1024 -> Cb; >=1024 -> Vt[n-1024,m]
// MODE 6: merged embedding (rows 0..M_CAT = fcat -> nmask1|nmask0;
//         rows M_CAT.. = aggFb -> (acc + b*rowb)*rowc)
// ---------------------------------------------------------------------------
template <int BM, int BN, int MODE, bool SPLIT>
__global__ __launch_bounds__(256) void mgemm(
    const bf16_t* __restrict__ A, const bf16_t* __restrict__ A2,
    const bf16_t* __restrict__ W, const float* __restrict__ bias,
    const bf16_t* __restrict__ res, const float* __restrict__ rowa,
    const float* __restrict__ rowa2, const float* __restrict__ rowb,
    const float* __restrict__ rowc,
    bf16_t* __restrict__ Cb, bf16_t* __restrict__ Vt,
    int M, int M1, int N, int K) {
  constexpr int FM = BM / 32, FN = BN / 32;
  constexpr int NCH = (BM + BN) / 16;
  constexpr int CPW = NCH / 4;
  __shared__ bf16_t lds[2][(BM + BN) * 32];
  const int t = threadIdx.x;
  const int w = t >> 6, lane = t & 63;
  const int g = lane >> 4, li = lane & 15;
  const int bm = blockIdx.x * BM, bn = blockIdx.y * BN;
  const int wr = (w >> 1) * (BM / 2), wc = (w & 1) * (BN / 2);
  f32x4_t acc[FM][FN] = {};

  auto stage = [&](int buf, int k0) {
#pragma unroll
    for (int c0 = 0; c0 < CPW; ++c0) {
      const int c = w * CPW + c0;
      const int row = c * 16 + (lane >> 2);
      const int gk = k0 + (lane & 3) * 8;
      const bf16_t* src;
      if (row < BM) {
        const int grow = bm + row;
        if (MODE == 6) {
          src = (grow < M_CAT) ? (A + (size_t)grow * K + gk)
                               : (A2 + (size_t)(grow - M_CAT) * K + gk);
        } else if (SPLIT) {
          src = (gk < 512) ? (A + (size_t)grow * 512 + gk)
                           : (A2 + (size_t)grow * 512 + (gk - 512));
        } else {
          src = A + (size_t)grow * K + gk;
        }
      } else {
        src = W + (size_t)(bn + row - BM) * K + gk;
      }
      gload16(src, &lds[buf][c * 512]);
    }
  };

  const int nk = K / 32;
  stage(0, 0);
  for (int ks = 0; ks < nk; ++ks) {
    __syncthreads();
    if (ks + 1 < nk) stage((ks + 1) & 1, (ks + 1) * 32);
    const bf16_t* As = &lds[ks & 1][0];
    const bf16_t* Bs = &lds[ks & 1][BM * 32];
    bf16x8_t af[FM], bfr[FN];
#pragma unroll
    for (int i = 0; i < FM; ++i)
      af[i] = *(const bf16x8_t*)(As + (wr + i * 16 + li) * 32 + g * 8);
#pragma unroll
    for (int j = 0; j < FN; ++j)
      bfr[j] = *(const bf16x8_t*)(Bs + (wc + j * 16 + li) * 32 + g * 8);
#pragma unroll
    for (int i = 0; i < FM; ++i)
#pragma unroll
      for (int j = 0; j < FN; ++j)
        acc[i][j] = __builtin_amdgcn_mfma_f32_16x16x32_bf16(
            af[i], bfr[j], acc[i][j], 0, 0, 0);
  }

  // epilogue: D frag: col n = li, row m = g*4 + reg (verified layout)
#pragma unroll
  for (int i = 0; i < FM; ++i) {
    const int mb = bm + wr + i * 16 + g * 4;
#pragma unroll
    for (int j = 0; j < FN; ++j) {
      const int n = bn + wc + j * 16 + li;
      if (MODE == 5) {
        const float bb = bias[n];
        if (n < 512) {
#pragma unroll
          for (int r = 0; r < 4; ++r)
            Cb[(size_t)(mb + r) * 1024 + n] = f2bf((acc[i][j][r] + bb) * QSCALE);
        } else if (n < 1024) {
#pragma unroll
          for (int r = 0; r < 4; ++r)
            Cb[(size_t)(mb + r) * 1024 + n] = f2bf(acc[i][j][r] + bb);
        } else {
          ushort4 o;
          o.x = f2bf(acc[i][j][0] + bb); o.y = f2bf(acc[i][j][1] + bb);
          o.z = f2bf(acc[i][j][2] + bb); o.w = f2bf(acc[i][j][3] + bb);
          *(ushort4*)(Vt + (size_t)(n - 1024) * M + mb) = o;
        }
      } else {
#pragma unroll
        for (int r = 0; r < 4; ++r) {
          const int m = mb + r;
          const float v = acc[i][j][r];
          if (MODE == 0) Cb[(size_t)m * N + n] = f2bf(v + bias[n]);
          if (MODE == 3) Cb[(size_t)m * N + n] = f2bf(fmaxf(v + bias[n], 0.f));
          if (MODE == 4) {
            const float ra = (m < M1) ? rowa[m] : rowa2[m - M1];
            Cb[(size_t)m * N + n] =
                f2bf((v + bias[n] + bf2f(res[(size_t)m * N + n])) * ra);
          }
          if (MODE == 6) {
            float val;
            if (m < M1) val = (v + bias[n]) * rowa[m];
            else if (m < M_CAT) val = (v + bias[n]) * rowa2[m - M1];
            else {
              const int mm = m - M_CAT;
              val = (v + bias[n] * rowb[mm]) * rowc[mm];
            }
            Cb[(size_t)m * N + n] = f2bf(val);
          }
        }
      }
    }
  }
}

// ---------------------------------------------------------------------------
// Flash attention, swapped-operand, double-buffered. NW waves; NQC q-frags
// per wave; two-pass PV (80KB LDS). Blocks >= nbig run the "tail" problem
// (qk2/vt2, N2 keys, direct write to attno2).
// ---------------------------------------------------------------------------
template <int NW, int NQC, int SPLITS>
__global__ __launch_bounds__(NW * 64) void flashT(
    const bf16_t* __restrict__ qk, const bf16_t* __restrict__ vt,
    bf16_t* __restrict__ attno, bf16_t* __restrict__ Ofb,
    float* __restrict__ Ml, int N, int VS,
    const bf16_t* __restrict__ qk2, const bf16_t* __restrict__ vt2,
    bf16_t* __restrict__ attno2, int nbig, int N2) {
  constexpr int QB = NW * NQC * 16;  // q rows per block
  constexpr int KCH = 16 / NW;       // staging chunks per wave (K and V each)
  __shared__ bf16_t Ks[2][64 * 128];
  __shared__ bf16_t Vs[2][128 * 64];
  __shared__ bf16_t Ps[NW][16 * 64];
  const int bid = blockIdx.x;
  int sp, h, qb, kvbase, nt;
  bool direct;
  const bf16_t *qkB, *vtB;
  bf16_t* attD;
  if (bid < nbig) {
    sp = bid % SPLITS;
    h = (bid / SPLITS) & 3;
    qb = bid / (4 * SPLITS);
    qkB = qk; vtB = vt;
    kvbase = sp * (N / SPLITS);
    nt = (N / SPLITS) >> 6;
    direct = (SPLITS == 1);
    attD = attno;
  } else {
    const int b2 = bid - nbig;
    sp = 0; h = b2 & 3; qb = 0;
    qkB = qk2; vtB = vt2;
    kvbase = 0;
    nt = N2 >> 6;
    direct = true;
    attD = attno2;
  }
  const int t = threadIdx.x, w = t >> 6, lane = t & 63;
  const int g = lane >> 4, li = lane & 15;

  bf16x8_t qf[NQC][4];
#pragma unroll
  for (int qc = 0; qc < NQC; ++qc) {
    const bf16_t* qrow =
        qkB + (size_t)(qb * QB + w * (NQC * 16) + qc * 16 + li) * 1024 + h * 128;
#pragma unroll
    for (int ks = 0; ks < 4; ++ks)
      qf[qc][ks] = *(const bf16x8_t*)(qrow + ks * 32 + g * 8);
  }

  // hoisted LDS byte offsets (xor-swizzled layout, round-2-verified)
  int koff[4], voff[2], pwoff[4];
#pragma unroll
  for (int ks = 0; ks < 4; ++ks)
    koff[ks] = li * 256 + (((ks * 4 + g) ^ (li & 7)) << 4);
#pragma unroll
  for (int ks = 0; ks < 2; ++ks)
    voff[ks] = li * 128 + (((ks * 4 + g) ^ (li & 7)) << 4);
#pragma unroll
  for (int mf = 0; mf < 4; ++mf)
    pwoff[mf] = li * 128 + (((mf * 2 + (g >> 1)) ^ (li & 7)) << 4) +
                ((g & 1) << 3);
  char* Pb = (char*)Ps + w * 2048;

  // running staging pointers (advance per tile)
  const bf16_t* kp[KCH];
  const bf16_t* vp[KCH];
#pragma unroll
  for (int i = 0; i < KCH; ++i) {
    const int c = w * KCH + i;
    const int rk = c * 4 + (lane >> 4);
    kp[i] = qkB + (size_t)(kvbase + rk) * 1024 + 512 + h * 128 +
            (((lane & 15) ^ (rk & 7)) * 8);
    const int rv = c * 8 + (lane >> 3);
    vp[i] = vtB + (size_t)(h * 128 + rv) * VS + kvbase +
            (((lane & 7) ^ (rv & 7)) * 8);
  }
  auto stage = [&](int buf) {
#pragma unroll
    for (int i = 0; i < KCH; ++i) {
      const int c = w * KCH + i;
      gload16(kp[i], &Ks[buf][c * 512]);
      kp[i] += (size_t)64 * 1024;
      gload16(vp[i], &Vs[buf][c * 512]);
      vp[i] += 64;
    }
  };

  f32x4_t acc[NQC][8] = {};
  float mrun[NQC], lrun[NQC];
#pragma unroll
  for (int qc = 0; qc < NQC; ++qc) { mrun[qc] = -1e30f; lrun[qc] = 0.f; }

  stage(0);
  for (int tt = 0; tt < nt; ++tt) {
    const int cur = tt & 1;
    __syncthreads();  // drains own stage loads (vmcnt(0)) -> cur resident
    if (tt + 1 < nt) stage(cur ^ 1);  // prefetch overlaps with compute below
    const char* Kb = (const char*)Ks + cur * 16384;
    const char* Vb = (const char*)Vs + cur * 16384;

    // S^T = K · Q^T : frag row kv = mf*16+g*4+r, col q = li (per qc)
    f32x4_t sf[NQC][4];
#pragma unroll
    for (int qc = 0; qc < NQC; ++qc)
#pragma unroll
      for (int mf = 0; mf < 4; ++mf) sf[qc][mf] = (f32x4_t){0.f, 0.f, 0.f, 0.f};
    __builtin_amdgcn_s_setprio(1);
#pragma unroll
    for (int ks = 0; ks < 4; ++ks) {
#pragma unroll
      for (int mf = 0; mf < 4; ++mf) {
        const bf16x8_t kf = *(const bf16x8_t*)(Kb + koff[ks] + mf * 4096);
#pragma unroll
        for (int qc = 0; qc < NQC; ++qc)
          sf[qc][mf] = __builtin_amdgcn_mfma_f32_16x16x32_bf16(
              kf, qf[qc][ks], sf[qc][mf], 0, 0, 0);
      }
    }
    __builtin_amdgcn_s_setprio(0);

    // online softmax (log2 domain); lane li owns q-rows (qc*16+li)
    float tmax[NQC];
#pragma unroll
    for (int qc = 0; qc < NQC; ++qc) {
      float tm = -1e30f;
#pragma unroll
      for (int mf = 0; mf < 4; ++mf)
#pragma unroll
        for (int r = 0; r < 4; ++r) tm = fmaxf(tm, sf[qc][mf][r]);
      tm = fmaxf(tm, __shfl_xor(tm, 16));
      tm = fmaxf(tm, __shfl_xor(tm, 32));
      tmax[qc] = tm;
    }
    float worst = tmax[0] - mrun[0];
#pragma unroll
    for (int qc = 1; qc < NQC; ++qc)
      worst = fmaxf(worst, tmax[qc] - mrun[qc]);
    if (!__all(worst <= 11.0f)) {  // defer-rescale (P bounded by 2^11)
#pragma unroll
      for (int qc = 0; qc < NQC; ++qc) {
        const float mnew = fmaxf(mrun[qc], tmax[qc]);
        const float fsc = exp2f(mrun[qc] - mnew);
        mrun[qc] = mnew;
        lrun[qc] *= fsc;
#pragma unroll
        for (int mf = 0; mf < 8; ++mf) acc[qc][mf] *= fsc;
      }
    }
#pragma unroll
    for (int qc = 0; qc < NQC; ++qc) {
      float lsum = 0.f;
#pragma unroll
      for (int mf = 0; mf < 4; ++mf)
#pragma unroll
        for (int r = 0; r < 4; ++r) {
          const float p = exp2f(sf[qc][mf][r] - mrun[qc]);
          sf[qc][mf][r] = p;
          lsum += p;
        }
      lsum += __shfl_xor(lsum, 16);
      lsum += __shfl_xor(lsum, 32);
      lrun[qc] += lsum;
    }

    // PV, one pass per qc: P -> per-wave LDS, then O^T += Vt · P^T.
    __builtin_amdgcn_s_setprio(1);
#pragma unroll
    for (int qc = 0; qc < NQC; ++qc) {
#pragma unroll
      for (int mf = 0; mf < 4; ++mf) {
        uint2 pv;
        pv.x = cvtpk(sf[qc][mf][0], sf[qc][mf][1]);
        pv.y = cvtpk(sf[qc][mf][2], sf[qc][mf][3]);
        *(uint2*)(Pb + pwoff[mf]) = pv;
      }
#pragma unroll
      for (int ks = 0; ks < 2; ++ks) {
        const bf16x8_t pf = *(const bf16x8_t*)(Pb + voff[ks]);
#pragma unroll
        for (int mf = 0; mf < 8; ++mf) {
          const bf16x8_t vf = *(const bf16x8_t*)(Vb + voff[ks] + mf * 2048);
          acc[qc][mf] = __builtin_amdgcn_mfma_f32_16x16x32_bf16(
              vf, pf, acc[qc][mf], 0, 0, 0);
        }
      }
    }
    __builtin_amdgcn_s_setprio(0);
  }

#pragma unroll
  for (int qc = 0; qc < NQC; ++qc) {
    const float invl = 1.f / lrun[qc];
    const int q = qb * QB + w * (NQC * 16) + qc * 16 + li;
    bf16_t* dst = direct ? (attD + (size_t)q * 512 + h * 128)
                         : (Ofb + ((size_t)sp * N + q) * 512 + h * 128);
#pragma unroll
    for (int mf = 0; mf < 8; ++mf) {
      ushort4 o;
      o.x = f2bf(acc[qc][mf][0] * invl); o.y = f2bf(acc[qc][mf][1] * invl);
      o.z = f2bf(acc[qc][mf][2] * invl); o.w = f2bf(acc[qc][mf][3] * invl);
      *(ushort4*)(dst + mf * 16 + g * 4) = o;
    }
    if (!direct && lane < 16) {
      float2 ml; ml.x = mrun[qc]; ml.y = lrun[qc];
      *(float2*)(Ml + ((size_t)(sp * 4 + h) * N + q) * 2) = ml;
    }
  }
}

// merge SPLITS normalized partials: w_s = l_s * 2^(m_s - m); out = Σ w_s O_s / Σ w_s
template <int SPLITS>
__global__ __launch_bounds__(256) void merge_attn(
    const bf16_t* __restrict__ Ofb, const float* __restrict__ Ml,
    bf16_t* __restrict__ attno, int N) {
  const int q = blockIdx.x, t = threadIdx.x;
#pragma unroll
  for (int half = 0; half < 2; ++half) {
    const int c = t + half * 256;
    const int h = c >> 7;
    float2 ml[SPLITS];
    float m = -1e30f;
#pragma unroll
    for (int s = 0; s < SPLITS; ++s) {
      ml[s] = ((const float2*)Ml)[(s * 4 + h) * N + q];
      m = fmaxf(m, ml[s].x);
    }
    float num = 0.f, den = 0.f;
#pragma unroll
    for (int s = 0; s < SPLITS; ++s) {
      const float wgt = ml[s].y * exp2f(ml[s].x - m);
      num += bf2f(Ofb[((size_t)s * N + q) * 512 + c]) * wgt;
      den += wgt;
    }
    attno[(size_t)q * 512 + c] = f2bf(num / den);
  }
}

// ---------------------------------------------------------------------------
__global__ __launch_bounds__(256) void add_ln(
    const bf16_t* __restrict__ X, const bf16_t* __restrict__ Y,
    const float* __restrict__ gg, const float* __restrict__ bb,
    bf16_t* __restrict__ out) {
  const int row = blockIdx.x, t = threadIdx.x;
  const size_t base = (size_t)row * 512;
  const float x0 = bf2f(X[base + t]) + bf2f(Y[base + t]);
  const float x1 = bf2f(X[base + 256 + t]) + bf2f(Y[base + 256 + t]);
  float s = x0 + x1, ss = x0 * x0 + x1 * x1;
#pragma unroll
  for (int o = 32; o > 0; o >>= 1) {
    s += __shfl_down(s, o);
    ss += __shfl_down(ss, o);
  }
  __shared__ float rs[4], rss[4], sm[2];
  const int wv = t >> 6, ln = t & 63;
  if (ln == 0) { rs[wv] = s; rss[wv] = ss; }
  __syncthreads();
  if (t == 0) {
    const float S = rs[0] + rs[1] + rs[2] + rs[3];
    const float SS = rss[0] + rss[1] + rss[2] + rss[3];
    const float mean = S * (1.f / 512.f);
    sm[0] = mean;
    sm[1] = rsqrtf(SS * (1.f / 512.f) - mean * mean + 1e-5f);
  }
  __syncthreads();
  const float mean = sm[0], rstd = sm[1];
  out[base + t] = f2bf((x0 - mean) * rstd * gg[t] + bb[t]);
  out[base + 256 + t] = f2bf((x1 - mean) * rstd * gg[t + 256] + bb[t + 256]);
}

// vectorized: 4 nodes per block, 64 lanes x float4 per node
__global__ __launch_bounds__(256) void agg_feats(
    const float* __restrict__ feats2, const int* __restrict__ nbm,
    const float* __restrict__ nm2, bf16_t* __restrict__ aggF,
    float* __restrict__ sw, float* __restrict__ invd) {
  const int node = blockIdx.x * 4 + (threadIdx.x >> 6);
  const int lane = threadIdx.x & 63;
  float4 acc = {0.f, 0.f, 0.f, 0.f};
  float ws = 0.f, nbs = 0.f;
#pragma unroll
  for (int j = 0; j < 16; ++j) {
    const float nb = (float)nbm[node * 16 + j];
    const float wj = nb * nm2[node * 16 + j];
    const float4 v =
        *(const float4*)(feats2 + (size_t)(node * 16 + j) * 256 + lane * 4);
    acc.x += wj * v.x; acc.y += wj * v.y;
    acc.z += wj * v.z; acc.w += wj * v.w;
    ws += wj;
    nbs += nb;
  }
  ushort4 o;
  o.x = f2bf(acc.x); o.y = f2bf(acc.y); o.z = f2bf(acc.z); o.w = f2bf(acc.w);
  *(ushort4*)(aggF + (size_t)node * 256 + lane * 4) = o;
  if (lane == 0) { sw[node] = ws; invd[node] = 1.f / fmaxf(nbs, 1.f); }
}

// vectorized: 4 nodes per block (one per wave), lane covers 8 cols (bf16x8)
__global__ __launch_bounds__(256) void agg_state(
    const bf16_t* __restrict__ src, const int* __restrict__ nbm,
    bf16_t* __restrict__ agg) {
  const int node = blockIdx.x * 4 + (threadIdx.x >> 6);
  const int lane = threadIdx.x & 63;
  float acc[8] = {};
  float nbs = 0.f;
#pragma unroll
  for (int j = 0; j < 16; ++j) {
    const float nb = (float)nbm[node * 16 + j];
    nbs += nb;
    const bf16x8_t v =
        *(const bf16x8_t*)(src + (size_t)(node * 16 + j) * 512 + lane * 8);
#pragma unroll
    for (int e = 0; e < 8; ++e) acc[e] += nb * bf2f((bf16_t)v[e]);
  }
  const float inv = 1.f / fmaxf(nbs, 1.f);
  bf16x8_t o;
#pragma unroll
  for (int e = 0; e < 8; ++e) o[e] = (short)f2bf(acc[e] * inv);
  *(bf16x8_t*)(agg + (size_t)node * 512 + lane * 8) = o;
}

// all fp32->bf16 conversions in one dispatch (float4-unit segments)
__global__ __launch_bounds__(256) void cvt_all(
    const float* __restrict__ s_emb, const float* __restrict__ s_sage,
    const float* __restrict__ s_qkv, const float* __restrict__ s_out,
    const float* __restrict__ s_f1, const float* __restrict__ s_f2,
    const float* __restrict__ s_ft0, const float* __restrict__ s_ft1,
    bf16_t* __restrict__ d_emb, bf16_t* __restrict__ d_sage,
    bf16_t* __restrict__ d_qkv, bf16_t* __restrict__ d_out,
    bf16_t* __restrict__ d_f1, bf16_t* __restrict__ d_f2,
    bf16_t* __restrict__ d_ft0, bf16_t* __restrict__ d_ft1) {
  int i = blockIdx.x * 256 + threadIdx.x;
  const float* s; bf16_t* d; int base;
  if (i < 32768)        { s = s_emb;  d = d_emb;  base = 0; }
  else if (i < 294912)  { s = s_sage; d = d_sage; base = 32768; }
  else if (i < 688128)  { s = s_qkv;  d = d_qkv;  base = 294912; }
  else if (i < 819200)  { s = s_out;  d = d_out;  base = 688128; }
  else if (i < 1081344) { s = s_f1;   d = d_f1;   base = 819200; }
  else if (i < 1343488) { s = s_f2;   d = d_f2;   base = 1081344; }
  else if (i < 1359872) { s = s_ft0;  d = d_ft0;  base = 1343488; }
  else                  { s = s_ft1;  d = d_ft1;  base = 1359872; }
  i -= base;
  const float4 v = ((const float4*)s)[i];
  ushort4 o;
  o.x = f2bf(v.x); o.y = f2bf(v.y); o.z = f2bf(v.z); o.w = f2bf(v.w);
  ((ushort4*)d)[i] = o;
}

__global__ __launch_bounds__(256) void cls_k(
    const bf16_t* __restrict__ s, const float* __restrict__ wc,
    const float* __restrict__ bc, float* __restrict__ out) {
  __shared__ float srow[512];
  const int m = blockIdx.x, t = threadIdx.x;
  srow[t] = bf2f(s[(size_t)m * 512 + t]);
  srow[t + 256] = bf2f(s[(size_t)m * 512 + 256 + t]);
  __syncthreads();
  if (t < 47) {
    float a = bc[t];
    const float* wr = wc + (size_t)t * 512;
    for (int k = 0; k < 512; ++k) a += srow[k] * wr[k];
    out[(size_t)m * 47 + t] = a;
  }
}

// ---------------------------------------------------------------------------
extern "C" void kernel_launch(void* const* d_in, const int* in_sizes, int n_in,
                              void* d_out, int out_size, void* d_ws,
                              size_t ws_size, hipStream_t stream) {
  const float* feats0 = (const float*)d_in[0];
  const float* feats1 = (const float*)d_in[1];
  const float* feats2 = (const float*)d_in[2];
  const float* nmask0 = (const float*)d_in[3];
  const float* nmask1 = (const float*)d_in[4];
  const float* nmask2 = (const float*)d_in[5];
  const int* nbmask0 = (const int*)d_in[6];
  const int* nbmask1 = (const int*)d_in[7];
  const float* emb_w = (const float*)d_in[8];
  const float* emb_b = (const float*)d_in[9];
  const float* sage_w = (const float*)d_in[10];
  const float* sage_b = (const float*)d_in[11];
  const float* qkv_w = (const float*)d_in[12];
  const float* qkv_b = (const float*)d_in[13];
  const float* out_w = (const float*)d_in[14];
  const float* out_b = (const float*)d_in[15];
  const float* n1_g = (const float*)d_in[16];
  const float* n1_b = (const float*)d_in[17];
  const float* n2_g = (const float*)d_in[18];
  const float* n2_b = (const float*)d_in[19];
  const float* ffn_w1 = (const float*)d_in[20];
  const float* ffn_b1 = (const float*)d_in[21];
  const float* ffn_w2 = (const float*)d_in[22];
  const float* ffn_b2 = (const float*)d_in[23];
  const float* cls_w = (const float*)d_in[24];
  const float* cls_b = (const float*)d_in[25];
  float* out = (float*)d_out;

  size_t off = 0;
  auto alloc = [&](size_t bytes) {
    void* r = (char*)d_ws + off;
    off += (bytes + 255) & ~(size_t)255;
    return r;
  };
  bf16_t* wemb = (bf16_t*)alloc((size_t)512 * 256 * 2);
  bf16_t* wsage = (bf16_t*)alloc((size_t)2 * 512 * 1024 * 2);
  bf16_t* wqkv = (bf16_t*)alloc((size_t)2 * 1536 * 512 * 2);
  bf16_t* wout = (bf16_t*)alloc((size_t)2 * 512 * 512 * 2);
  bf16_t* wf1 = (bf16_t*)alloc((size_t)2 * 1024 * 512 * 2);
  bf16_t* wf2 = (bf16_t*)alloc((size_t)2 * 512 * 1024 * 2);
  bf16_t* fcat = (bf16_t*)alloc((size_t)M_CAT * 256 * 2);   // feats1|feats0
  bf16_t* s_cat = (bf16_t*)alloc((size_t)2 * M_CAT * 512 * 2);
  bf16_t* agg_cat = s_cat + (size_t)M_CAT * 512;
  bf16_t* scat_o = (bf16_t*)alloc((size_t)M_CAT * 512 * 2); // s1b|s0b
  bf16_t* aggFb = (bf16_t*)alloc((size_t)4096 * 256 * 2);
  float* swv = (float*)alloc((size_t)4096 * 4);
  float* invd = (float*)alloc((size_t)4096 * 4);
  bf16_t* agg256 = (bf16_t*)alloc((size_t)256 * 512 * 2);
  bf16_t* s0f = (bf16_t*)alloc((size_t)256 * 512 * 2);
  bf16_t* tmpb = (bf16_t*)alloc((size_t)M_CAT * 512 * 2);
  bf16_t* h1 = (bf16_t*)alloc((size_t)M_CAT * 512 * 2);
  bf16_t* h2 = (bf16_t*)alloc((size_t)M_CAT * 512 * 2);
  bf16_t* qkb = (bf16_t*)alloc((size_t)M_CAT * 1024 * 2);
  bf16_t* vt = (bf16_t*)alloc((size_t)512 * M_CAT * 2);
  bf16_t* attno = (bf16_t*)alloc((size_t)M_CAT * 512 * 2);
  bf16_t* f1o = (bf16_t*)alloc((size_t)M_CAT * 1024 * 2);
  bf16_t* Ofb = (bf16_t*)alloc((size_t)NSPLIT * 4096 * 512 * 2);
  float* Ml = (float*)alloc((size_t)NSPLIT * 4 * 4096 * 2 * 4);

  // weight + feature conversion; feats1 -> fcat rows 0..4096, feats0 -> tail
  cvt_all<<<6336, 256, 0, stream>>>(emb_w, sage_w, qkv_w, out_w, ffn_w1,
                                    ffn_w2, feats0, feats1, wemb, wsage, wqkv,
                                    wout, wf1, wf2, fcat + (size_t)4096 * 256,
                                    fcat);

  // depth-2 masked feature aggregation
  agg_feats<<<1024, 256, 0, stream>>>(feats2, nbmask1, nmask2, aggFb, swv, invd);
  // merged embedding: rows 0..4352 -> s_cat; rows 4352..8448 -> agg_cat[0..4096]
  mgemm<64, 64, 6, false><<<dim3((M_CAT + M_BIG) / 64, 8), 256, 0, stream>>>(
      fcat, aggFb, wemb, emb_b, nullptr, nmask1, nmask0, swv, invd, s_cat,
      nullptr, M_CAT + M_BIG, M_BIG, 512, 256);
  // depth-0 aggregation of OLD s1 (agg_cat rows 4096..4352)
  agg_state<<<64, 256, 0, stream>>>(s_cat, nbmask0,
                                    agg_cat + (size_t)M_BIG * 512);

  // ---- layer 0, fused depth-1 (4096 rows) + depth-0 (256 rows) ----
  mgemm<64, 64, 0, true><<<dim3(M_CAT / 64, 8), 256, 0, stream>>>(
      s_cat, agg_cat, wsage, sage_b, nullptr, nullptr, nullptr, nullptr,
      nullptr, tmpb, nullptr, M_CAT, 0, 512, 1024);
  add_ln<<<M_CAT, 256, 0, stream>>>(s_cat, tmpb, n1_g, n1_b, h1);
  mgemm<64, 64, 5, false><<<dim3(M_CAT / 64, 24), 256, 0, stream>>>(
      h1, nullptr, wqkv, qkv_b, nullptr, nullptr, nullptr, nullptr, nullptr,
      qkb, vt, M_CAT, 0, 1536, 512);
  // unified flash: 256 big blocks (4096 rows, SPLITS=4) + 4 tail blocks (256)
  flashT<8, 2, NSPLIT><<<(M_BIG / 256) * 4 * NSPLIT + 4, 512, 0, stream>>>(
      qkb, vt, nullptr, Ofb, Ml, M_BIG, M_CAT, qkb + (size_t)M_BIG * 1024,
      vt + M_BIG, attno + (size_t)M_BIG * 512, (M_BIG / 256) * 4 * NSPLIT, 256);
  merge_attn<NSPLIT><<<M_BIG, 256, 0, stream>>>(Ofb, Ml, attno, M_BIG);
  mgemm<64, 64, 0, false><<<dim3(M_CAT / 64, 8), 256, 0, stream>>>(
      attno, nullptr, wout, out_b, nullptr, nullptr, nullptr, nullptr, nullptr,
      tmpb, nullptr, M_CAT, 0, 512, 512);
  add_ln<<<M_CAT, 256, 0, stream>>>(h1, tmpb, n2_g, n2_b, h2);
  mgemm<64, 64, 3, false><<<dim3(M_CAT / 64, 16), 256, 0, stream>>>(
      h2, nullptr, wf1, ffn_b1, nullptr, nullptr, nullptr, nullptr, nullptr,
      f1o, nullptr, M_CAT, 0, 1024, 512);
  mgemm<64, 64, 4, false><<<dim3(M_CAT / 64, 8), 256, 0, stream>>>(
      f1o, nullptr, wf2, ffn_b2, h2, nmask1, nmask0, nullptr, nullptr, scat_o,
      nullptr, M_CAT, M_BIG, 512, 1024);

  // ---- layer 1, depth 0 (n=256): sf = scat_o rows 4096.., children = rows 0..4096
  const bf16_t* s1b = scat_o;
  const bf16_t* s0b = scat_o + (size_t)M_BIG * 512;
  agg_state<<<64, 256, 0, stream>>>(s1b, nbmask0, agg256);
  const bf16_t* wsage1 = wsage + 512 * 1024;
  const bf16_t* wqkv1 = wqkv + 1536 * 512;
  const bf16_t* wout1 = wout + 512 * 512;
  const bf16_t* wf11 = wf1 + 1024 * 512;
  const bf16_t* wf21 = wf2 + 512 * 1024;
  mgemm<64, 64, 0, true><<<dim3(4, 8), 256, 0, stream>>>(
      s0b, agg256, wsage1, sage_b + 512, nullptr, nullptr, nullptr, nullptr,
      nullptr, tmpb, nullptr, 256, 0, 512, 1024);
  add_ln<<<256, 256, 0, stream>>>(s0b, tmpb, n1_g + 512, n1_b + 512, h1);
  mgemm<64, 64, 5, false><<<dim3(4, 24), 256, 0, stream>>>(
      h1, nullptr, wqkv1, qkv_b + 1536, nullptr, nullptr, nullptr, nullptr,
      nullptr, qkb, vt, 256, 0, 1536, 512);
  flashT<4, 1, 1><<<(256 / 64) * 4, 256, 0, stream>>>(
      qkb, vt, attno, nullptr, nullptr, 256, 256, nullptr, nullptr, nullptr,
      (256 / 64) * 4, 0);
  mgemm<64, 64, 0, false><<<dim3(4, 8), 256, 0, stream>>>(
      attno, nullptr, wout1, out_b + 512, nullptr, nullptr, nullptr, nullptr,
      nullptr, tmpb, nullptr, 256, 0, 512, 512);
  add_ln<<<256, 256, 0, stream>>>(h1, tmpb, n2_g + 512, n2_b + 512, h2);
  mgemm<64, 64, 3, false><<<dim3(4, 16), 256, 0, stream>>>(
      h2, nullptr, wf11, ffn_b1 + 1024, nullptr, nullptr, nullptr, nullptr,
      nullptr, f1o, nullptr, 256, 0, 1024, 512);
  mgemm<64, 64, 4, false><<<dim3(4, 8), 256, 0, stream>>>(
      f1o, nullptr, wf21, ffn_b2 + 512, h2, nmask0, nmask0, nullptr, nullptr,
      s0f, nullptr, 256, 256, 512, 1024);

  cls_k<<<256, 256, 0, stream>>>(s0f, cls_w, cls_b, out);
}

// Round 16
// 260.778 us; speedup vs baseline: 1.7482x; 1.0228x over previous
//
#include <hip/hip_runtime.h>
#include <math.h>

// ---------------------------------------------------------------------------
// GraphTransformer, bf16 MFMA. Round 16: exact revert to round-12 (best:
// 260.9us). Flash: SPLITS=4, QB=256, NW=8, NQC=2, two-pass PV, 256 blocks,
// separate small-flash dispatches. Merged M=8448 embedding GEMM. MODE-0 +
// add_ln LN path (fence-free).
// NL=2, H=4, C=512, IN=256, F=16, B=256, NC=47, DH=128
// ---------------------------------------------------------------------------

typedef unsigned short bf16_t;
typedef __attribute__((ext_vector_type(8))) short bf16x8_t;
typedef __attribute__((ext_vector_type(4))) float f32x4_t;

#define M_BIG 4096
#define M_CAT 4352  // 4096 + 256
#define NSPLIT 4

__device__ __forceinline__ bf16_t f2bf(float f) {
  union { float f; unsigned u; } v; v.f = f;
  unsigned r = v.u + 0x7FFFu + ((v.u >> 16) & 1u);
  return (bf16_t)(r >> 16);
}
__device__ __forceinline__ float bf2f(bf16_t u) {
  union { unsigned u; float f; } v; v.u = ((unsigned)u) << 16; return v.f;
}
__device__ __forceinline__ unsigned cvtpk(float lo, float hi) {
  unsigned r;
  asm("v_cvt_pk_bf16_f32 %0, %1, %2" : "=v"(r) : "v"(lo), "v"(hi));
  return r;
}
__device__ __forceinline__ void gload16(const void* g, void* l) {
  __builtin_amdgcn_global_load_lds(
      (const __attribute__((address_space(1))) unsigned int*)g,
      (__attribute__((address_space(3))) unsigned int*)l, 16, 0, 0);
}

// Q pre-scale: 1/sqrt(128) * log2(e)  (softmax runs in log2 domain)
#define QSCALE (0.08838834764831845f * 1.4426950408889634f)

// ---------------------------------------------------------------------------
// GEMM: C[M,N] = A[M,K] @ W[N,K]^T + epilogue. A,W bf16; accum fp32.
// MODE 0: Cb = acc + b
// MODE 3: Cb = relu(acc + b)                    (ffn1)
// MODE 4: Cb = (acc + b + res[m,n]) * (m<M1?rowa:rowa2)  (ffn2+resid+nmask)
// MODE 5: qkv: n<512 -> Cb[m,1024]*QSCALE; <1024 -> Cb; >=1024 -> Vt[n-1024,m]
// MODE 6: merged embedding (rows 0..M_CAT = fcat -> nmask1|nmask0;
//         rows M_CAT.. = aggFb -> (acc + b*rowb)*rowc)
// ---------------------------------------------------------------------------
template <int BM, int BN, int MODE, bool SPLIT>
__global__ __launch_bounds__(256) void mgemm(
    const bf16_t* __restrict__ A, const bf16_t* __restrict__ A2,
    const bf16_t* __restrict__ W, const float* __restrict__ bias,
    const bf16_t* __restrict__ res, const float* __restrict__ rowa,
    const float* __restrict__ rowa2, const float* __restrict__ rowb,
    const float* __restrict__ rowc,
    bf16_t* __restrict__ Cb, bf16_t* __restrict__ Vt,
    int M, int M1, int N, int K) {
  constexpr int FM = BM / 32, FN = BN / 32;
  constexpr int NCH = (BM + BN) / 16;
  constexpr int CPW = NCH / 4;
  __shared__ bf16_t lds[2][(BM + BN) * 32];
  const int t = threadIdx.x;
  const int w = t >> 6, lane = t & 63;
  const int g = lane >> 4, li = lane & 15;
  const int bm = blockIdx.x * BM, bn = blockIdx.y * BN;
  const int wr = (w >> 1) * (BM / 2), wc = (w & 1) * (BN / 2);
  f32x4_t acc[FM][FN] = {};

  auto stage = [&](int buf, int k0) {
#pragma unroll
    for (int c0 = 0; c0 < CPW; ++c0) {
      const int c = w * CPW + c0;
      const int row = c * 16 + (lane >> 2);
      const int gk = k0 + (lane & 3) * 8;
      const bf16_t* src;
      if (row < BM) {
        const int grow = bm + row;
        if (MODE == 6) {
          src = (grow < M_CAT) ? (A + (size_t)grow * K + gk)
                               : (A2 + (size_t)(grow - M_CAT) * K + gk);
        } else if (SPLIT) {
          src = (gk < 512) ? (A + (size_t)grow * 512 + gk)
                           : (A2 + (size_t)grow * 512 + (gk - 512));
        } else {
          src = A + (size_t)grow * K + gk;
        }
      } else {
        src = W + (size_t)(bn + row - BM) * K + gk;
      }
      gload16(src, &lds[buf][c * 512]);
    }
  };

  const int nk = K / 32;
  stage(0, 0);
  for (int ks = 0; ks < nk; ++ks) {
    __syncthreads();
    if (ks + 1 < nk) stage((ks + 1) & 1, (ks + 1) * 32);
    const bf16_t* As = &lds[ks & 1][0];
    const bf16_t* Bs = &lds[ks & 1][BM * 32];
    bf16x8_t af[FM], bfr[FN];
#pragma unroll
    for (int i = 0; i < FM; ++i)
      af[i] = *(const bf16x8_t*)(As + (wr + i * 16 + li) * 32 + g * 8);
#pragma unroll
    for (int j = 0; j < FN; ++j)
      bfr[j] = *(const bf16x8_t*)(Bs + (wc + j * 16 + li) * 32 + g * 8);
#pragma unroll
    for (int i = 0; i < FM; ++i)
#pragma unroll
      for (int j = 0; j < FN; ++j)
        acc[i][j] = __builtin_amdgcn_mfma_f32_16x16x32_bf16(
            af[i], bfr[j], acc[i][j], 0, 0, 0);
  }

  // epilogue: D frag: col n = li, row m = g*4 + reg (verified layout)
#pragma unroll
  for (int i = 0; i < FM; ++i) {
    const int mb = bm + wr + i * 16 + g * 4;
#pragma unroll
    for (int j = 0; j < FN; ++j) {
      const int n = bn + wc + j * 16 + li;
      if (MODE == 5) {
        const float bb = bias[n];
        if (n < 512) {
#pragma unroll
          for (int r = 0; r < 4; ++r)
            Cb[(size_t)(mb + r) * 1024 + n] = f2bf((acc[i][j][r] + bb) * QSCALE);
        } else if (n < 1024) {
#pragma unroll
          for (int r = 0; r < 4; ++r)
            Cb[(size_t)(mb + r) * 1024 + n] = f2bf(acc[i][j][r] + bb);
        } else {
          ushort4 o;
          o.x = f2bf(acc[i][j][0] + bb); o.y = f2bf(acc[i][j][1] + bb);
          o.z = f2bf(acc[i][j][2] + bb); o.w = f2bf(acc[i][j][3] + bb);
          *(ushort4*)(Vt + (size_t)(n - 1024) * M + mb) = o;
        }
      } else {
#pragma unroll
        for (int r = 0; r < 4; ++r) {
          const int m = mb + r;
          const float v = acc[i][j][r];
          if (MODE == 0) Cb[(size_t)m * N + n] = f2bf(v + bias[n]);
          if (MODE == 3) Cb[(size_t)m * N + n] = f2bf(fmaxf(v + bias[n], 0.f));
          if (MODE == 4) {
            const float ra = (m < M1) ? rowa[m] : rowa2[m - M1];
            Cb[(size_t)m * N + n] =
                f2bf((v + bias[n] + bf2f(res[(size_t)m * N + n])) * ra);
          }
          if (MODE == 6) {
            float val;
            if (m < M1) val = (v + bias[n]) * rowa[m];
            else if (m < M_CAT) val = (v + bias[n]) * rowa2[m - M1];
            else {
              const int mm = m - M_CAT;
              val = (v + bias[n] * rowb[mm]) * rowc[mm];
            }
            Cb[(size_t)m * N + n] = f2bf(val);
          }
        }
      }
    }
  }
}

// ---------------------------------------------------------------------------
// Flash attention, swapped-operand, double-buffered. NW waves; NQC q-frags
// per wave. Two-pass PV (Ps = 2KB/wave -> LDS 80KB).
// qk: [*][1024] = Q*QSCALE|K (base pre-offset). vt: base pre-offset, stride VS.
// bid = qb*(4*SPLITS) + h*SPLITS + sp.
// ---------------------------------------------------------------------------
template <int NW, int NQC, int SPLITS>
__global__ __launch_bounds__(NW * 64) void flashT(
    const bf16_t* __restrict__ qk, const bf16_t* __restrict__ vt,
    bf16_t* __restrict__ attno, bf16_t* __restrict__ Ofb,
    float* __restrict__ Ml, int N, int VS) {
  constexpr int QB = NW * NQC * 16;  // q rows per block
  constexpr int KCH = 16 / NW;       // staging chunks per wave (K and V each)
  __shared__ bf16_t Ks[2][64 * 128];
  __shared__ bf16_t Vs[2][128 * 64];
  __shared__ bf16_t Ps[NW][16 * 64];
  const int bid = blockIdx.x;
  const int sp = bid % SPLITS;
  const int h = (bid / SPLITS) & 3;
  const int qb = bid / (4 * SPLITS);
  const int t = threadIdx.x, w = t >> 6, lane = t & 63;
  const int g = lane >> 4, li = lane & 15;
  const int kvbase = sp * (N / SPLITS);
  const int nt = (N / SPLITS) >> 6;

  bf16x8_t qf[NQC][4];
#pragma unroll
  for (int qc = 0; qc < NQC; ++qc) {
    const bf16_t* qrow =
        qk + (size_t)(qb * QB + w * (NQC * 16) + qc * 16 + li) * 1024 + h * 128;
#pragma unroll
    for (int ks = 0; ks < 4; ++ks)
      qf[qc][ks] = *(const bf16x8_t*)(qrow + ks * 32 + g * 8);
  }

  // hoisted LDS byte offsets (xor-swizzled layout, round-2-verified)
  int koff[4], voff[2], pwoff[4];
#pragma unroll
  for (int ks = 0; ks < 4; ++ks)
    koff[ks] = li * 256 + (((ks * 4 + g) ^ (li & 7)) << 4);
#pragma unroll
  for (int ks = 0; ks < 2; ++ks)
    voff[ks] = li * 128 + (((ks * 4 + g) ^ (li & 7)) << 4);
#pragma unroll
  for (int mf = 0; mf < 4; ++mf)
    pwoff[mf] = li * 128 + (((mf * 2 + (g >> 1)) ^ (li & 7)) << 4) +
                ((g & 1) << 3);
  char* Pb = (char*)Ps + w * 2048;

  // running staging pointers (advance per tile)
  const bf16_t* kp[KCH];
  const bf16_t* vp[KCH];
#pragma unroll
  for (int i = 0; i < KCH; ++i) {
    const int c = w * KCH + i;
    const int rk = c * 4 + (lane >> 4);
    kp[i] = qk + (size_t)(kvbase + rk) * 1024 + 512 + h * 128 +
            (((lane & 15) ^ (rk & 7)) * 8);
    const int rv = c * 8 + (lane >> 3);
    vp[i] = vt + (size_t)(h * 128 + rv) * VS + kvbase +
            (((lane & 7) ^ (rv & 7)) * 8);
  }
  auto stage = [&](int buf) {
#pragma unroll
    for (int i = 0; i < KCH; ++i) {
      const int c = w * KCH + i;
      gload16(kp[i], &Ks[buf][c * 512]);
      kp[i] += (size_t)64 * 1024;
      gload16(vp[i], &Vs[buf][c * 512]);
      vp[i] += 64;
    }
  };

  f32x4_t acc[NQC][8] = {};
  float mrun[NQC], lrun[NQC];
#pragma unroll
  for (int qc = 0; qc < NQC; ++qc) { mrun[qc] = -1e30f; lrun[qc] = 0.f; }

  stage(0);
  for (int tt = 0; tt < nt; ++tt) {
    const int cur = tt & 1;
    __syncthreads();  // drains own stage loads (vmcnt(0)) -> cur resident
    if (tt + 1 < nt) stage(cur ^ 1);  // prefetch overlaps with compute below
    const char* Kb = (const char*)Ks + cur * 16384;
    const char* Vb = (const char*)Vs + cur * 16384;

    // S^T = K · Q^T : frag row kv = mf*16+g*4+r, col q = li (per qc)
    f32x4_t sf[NQC][4];
#pragma unroll
    for (int qc = 0; qc < NQC; ++qc)
#pragma unroll
      for (int mf = 0; mf < 4; ++mf) sf[qc][mf] = (f32x4_t){0.f, 0.f, 0.f, 0.f};
    __builtin_amdgcn_s_setprio(1);
#pragma unroll
    for (int ks = 0; ks < 4; ++ks) {
#pragma unroll
      for (int mf = 0; mf < 4; ++mf) {
        const bf16x8_t kf = *(const bf16x8_t*)(Kb + koff[ks] + mf * 4096);
#pragma unroll
        for (int qc = 0; qc < NQC; ++qc)
          sf[qc][mf] = __builtin_amdgcn_mfma_f32_16x16x32_bf16(
              kf, qf[qc][ks], sf[qc][mf], 0, 0, 0);
      }
    }
    __builtin_amdgcn_s_setprio(0);

    // online softmax (log2 domain); lane li owns q-rows (qc*16+li)
    float tmax[NQC];
#pragma unroll
    for (int qc = 0; qc < NQC; ++qc) {
      float tm = -1e30f;
#pragma unroll
      for (int mf = 0; mf < 4; ++mf)
#pragma unroll
        for (int r = 0; r < 4; ++r) tm = fmaxf(tm, sf[qc][mf][r]);
      tm = fmaxf(tm, __shfl_xor(tm, 16));
      tm = fmaxf(tm, __shfl_xor(tm, 32));
      tmax[qc] = tm;
    }
    float worst = tmax[0] - mrun[0];
#pragma unroll
    for (int qc = 1; qc < NQC; ++qc)
      worst = fmaxf(worst, tmax[qc] - mrun[qc]);
    if (!__all(worst <= 11.0f)) {  // defer-rescale (P bounded by 2^11)
#pragma unroll
      for (int qc = 0; qc < NQC; ++qc) {
        const float mnew = fmaxf(mrun[qc], tmax[qc]);
        const float fsc = exp2f(mrun[qc] - mnew);
        mrun[qc] = mnew;
        lrun[qc] *= fsc;
#pragma unroll
        for (int mf = 0; mf < 8; ++mf) acc[qc][mf] *= fsc;
      }
    }
#pragma unroll
    for (int qc = 0; qc < NQC; ++qc) {
      float lsum = 0.f;
#pragma unroll
      for (int mf = 0; mf < 4; ++mf)
#pragma unroll
        for (int r = 0; r < 4; ++r) {
          const float p = exp2f(sf[qc][mf][r] - mrun[qc]);
          sf[qc][mf][r] = p;
          lsum += p;
        }
      lsum += __shfl_xor(lsum, 16);
      lsum += __shfl_xor(lsum, 32);
      lrun[qc] += lsum;
    }

    // PV, one pass per qc: P -> per-wave LDS, then O^T += Vt · P^T.
    __builtin_amdgcn_s_setprio(1);
#pragma unroll
    for (int qc = 0; qc < NQC; ++qc) {
#pragma unroll
      for (int mf = 0; mf < 4; ++mf) {
        uint2 pv;
        pv.x = cvtpk(sf[qc][mf][0], sf[qc][mf][1]);
        pv.y = cvtpk(sf[qc][mf][2], sf[qc][mf][3]);
        *(uint2*)(Pb + pwoff[mf]) = pv;
      }
#pragma unroll
      for (int ks = 0; ks < 2; ++ks) {
        const bf16x8_t pf = *(const bf16x8_t*)(Pb + voff[ks]);
#pragma unroll
        for (int mf = 0; mf < 8; ++mf) {
          const bf16x8_t vf = *(const bf16x8_t*)(Vb + voff[ks] + mf * 2048);
          acc[qc][mf] = __builtin_amdgcn_mfma_f32_16x16x32_bf16(
              vf, pf, acc[qc][mf], 0, 0, 0);
        }
      }
    }
    __builtin_amdgcn_s_setprio(0);
  }

#pragma unroll
  for (int qc = 0; qc < NQC; ++qc) {
    const float invl = 1.f / lrun[qc];
    const int q = qb * QB + w * (NQC * 16) + qc * 16 + li;
    bf16_t* dst = (SPLITS == 1) ? (attno + (size_t)q * 512 + h * 128)
                                : (Ofb + ((size_t)sp * N + q) * 512 + h * 128);
#pragma unroll
    for (int mf = 0; mf < 8; ++mf) {
      ushort4 o;
      o.x = f2bf(acc[qc][mf][0] * invl); o.y = f2bf(acc[qc][mf][1] * invl);
      o.z = f2bf(acc[qc][mf][2] * invl); o.w = f2bf(acc[qc][mf][3] * invl);
      *(ushort4*)(dst + mf * 16 + g * 4) = o;
    }
    if (SPLITS > 1 && lane < 16) {
      float2 ml; ml.x = mrun[qc]; ml.y = lrun[qc];
      *(float2*)(Ml + ((size_t)(sp * 4 + h) * N + q) * 2) = ml;
    }
  }
}

// merge SPLITS normalized partials: w_s = l_s * 2^(m_s - m); out = Σ w_s O_s / Σ w_s
template <int SPLITS>
__global__ __launch_bounds__(256) void merge_attn(
    const bf16_t* __restrict__ Ofb, const float* __restrict__ Ml,
    bf16_t* __restrict__ attno, int N) {
  const int q = blockIdx.x, t = threadIdx.x;
#pragma unroll
  for (int half = 0; half < 2; ++half) {
    const int c = t + half * 256;
    const int h = c >> 7;
    float2 ml[SPLITS];
    float m = -1e30f;
#pragma unroll
    for (int s = 0; s < SPLITS; ++s) {
      ml[s] = ((const float2*)Ml)[(s * 4 + h) * N + q];
      m = fmaxf(m, ml[s].x);
    }
    float num = 0.f, den = 0.f;
#pragma unroll
    for (int s = 0; s < SPLITS; ++s) {
      const float wgt = ml[s].y * exp2f(ml[s].x - m);
      num += bf2f(Ofb[((size_t)s * N + q) * 512 + c]) * wgt;
      den += wgt;
    }
    attno[(size_t)q * 512 + c] = f2bf(num / den);
  }
}

// ---------------------------------------------------------------------------
__global__ __launch_bounds__(256) void add_ln(
    const bf16_t* __restrict__ X, const bf16_t* __restrict__ Y,
    const float* __restrict__ gg, const float* __restrict__ bb,
    bf16_t* __restrict__ out) {
  const int row = blockIdx.x, t = threadIdx.x;
  const size_t base = (size_t)row * 512;
  const float x0 = bf2f(X[base + t]) + bf2f(Y[base + t]);
  const float x1 = bf2f(X[base + 256 + t]) + bf2f(Y[base + 256 + t]);
  float s = x0 + x1, ss = x0 * x0 + x1 * x1;
#pragma unroll
  for (int o = 32; o > 0; o >>= 1) {
    s += __shfl_down(s, o);
    ss += __shfl_down(ss, o);
  }
  __shared__ float rs[4], rss[4], sm[2];
  const int wv = t >> 6, ln = t & 63;
  if (ln == 0) { rs[wv] = s; rss[wv] = ss; }
  __syncthreads();
  if (t == 0) {
    const float S = rs[0] + rs[1] + rs[2] + rs[3];
    const float SS = rss[0] + rss[1] + rss[2] + rss[3];
    const float mean = S * (1.f / 512.f);
    sm[0] = mean;
    sm[1] = rsqrtf(SS * (1.f / 512.f) - mean * mean + 1e-5f);
  }
  __syncthreads();
  const float mean = sm[0], rstd = sm[1];
  out[base + t] = f2bf((x0 - mean) * rstd * gg[t] + bb[t]);
  out[base + 256 + t] = f2bf((x1 - mean) * rstd * gg[t + 256] + bb[t + 256]);
}

// vectorized: 4 nodes per block, 64 lanes x float4 per node
__global__ __launch_bounds__(256) void agg_feats(
    const float* __restrict__ feats2, const int* __restrict__ nbm,
    const float* __restrict__ nm2, bf16_t* __restrict__ aggF,
    float* __restrict__ sw, float* __restrict__ invd) {
  const int node = blockIdx.x * 4 + (threadIdx.x >> 6);
  const int lane = threadIdx.x & 63;
  float4 acc = {0.f, 0.f, 0.f, 0.f};
  float ws = 0.f, nbs = 0.f;
#pragma unroll
  for (int j = 0; j < 16; ++j) {
    const float nb = (float)nbm[node * 16 + j];
    const float wj = nb * nm2[node * 16 + j];
    const float4 v =
        *(const float4*)(feats2 + (size_t)(node * 16 + j) * 256 + lane * 4);
    acc.x += wj * v.x; acc.y += wj * v.y;
    acc.z += wj * v.z; acc.w += wj * v.w;
    ws += wj;
    nbs += nb;
  }
  ushort4 o;
  o.x = f2bf(acc.x); o.y = f2bf(acc.y); o.z = f2bf(acc.z); o.w = f2bf(acc.w);
  *(ushort4*)(aggF + (size_t)node * 256 + lane * 4) = o;
  if (lane == 0) { sw[node] = ws; invd[node] = 1.f / fmaxf(nbs, 1.f); }
}

// vectorized: 4 nodes per block (one per wave), lane covers 8 cols (bf16x8)
__global__ __launch_bounds__(256) void agg_state(
    const bf16_t* __restrict__ src, const int* __restrict__ nbm,
    bf16_t* __restrict__ agg) {
  const int node = blockIdx.x * 4 + (threadIdx.x >> 6);
  const int lane = threadIdx.x & 63;
  float acc[8] = {};
  float nbs = 0.f;
#pragma unroll
  for (int j = 0; j < 16; ++j) {
    const float nb = (float)nbm[node * 16 + j];
    nbs += nb;
    const bf16x8_t v =
        *(const bf16x8_t*)(src + (size_t)(node * 16 + j) * 512 + lane * 8);
#pragma unroll
    for (int e = 0; e < 8; ++e) acc[e] += nb * bf2f((bf16_t)v[e]);
  }
  const float inv = 1.f / fmaxf(nbs, 1.f);
  bf16x8_t o;
#pragma unroll
  for (int e = 0; e < 8; ++e) o[e] = (short)f2bf(acc[e] * inv);
  *(bf16x8_t*)(agg + (size_t)node * 512 + lane * 8) = o;
}

// all fp32->bf16 conversions in one dispatch (float4-unit segments)
__global__ __launch_bounds__(256) void cvt_all(
    const float* __restrict__ s_emb, const float* __restrict__ s_sage,
    const float* __restrict__ s_qkv, const float* __restrict__ s_out,
    const float* __restrict__ s_f1, const float* __restrict__ s_f2,
    const float* __restrict__ s_ft0, const float* __restrict__ s_ft1,
    bf16_t* __restrict__ d_emb, bf16_t* __restrict__ d_sage,
    bf16_t* __restrict__ d_qkv, bf16_t* __restrict__ d_out,
    bf16_t* __restrict__ d_f1, bf16_t* __restrict__ d_f2,
    bf16_t* __restrict__ d_ft0, bf16_t* __restrict__ d_ft1) {
  int i = blockIdx.x * 256 + threadIdx.x;
  const float* s; bf16_t* d; int base;
  if (i < 32768)        { s = s_emb;  d = d_emb;  base = 0; }
  else if (i < 294912)  { s = s_sage; d = d_sage; base = 32768; }
  else if (i < 688128)  { s = s_qkv;  d = d_qkv;  base = 294912; }
  else if (i < 819200)  { s = s_out;  d = d_out;  base = 688128; }
  else if (i < 1081344) { s = s_f1;   d = d_f1;   base = 819200; }
  else if (i < 1343488) { s = s_f2;   d = d_f2;   base = 1081344; }
  else if (i < 1359872) { s = s_ft0;  d = d_ft0;  base = 1343488; }
  else                  { s = s_ft1;  d = d_ft1;  base = 1359872; }
  i -= base;
  const float4 v = ((const float4*)s)[i];
  ushort4 o;
  o.x = f2bf(v.x); o.y = f2bf(v.y); o.z = f2bf(v.z); o.w = f2bf(v.w);
  ((ushort4*)d)[i] = o;
}

__global__ __launch_bounds__(256) void cls_k(
    const bf16_t* __restrict__ s, const float* __restrict__ wc,
    const float* __restrict__ bc, float* __restrict__ out) {
  __shared__ float srow[512];
  const int m = blockIdx.x, t = threadIdx.x;
  srow[t] = bf2f(s[(size_t)m * 512 + t]);
  srow[t + 256] = bf2f(s[(size_t)m * 512 + 256 + t]);
  __syncthreads();
  if (t < 47) {
    float a = bc[t];
    const float* wr = wc + (size_t)t * 512;
    for (int k = 0; k < 512; ++k) a += srow[k] * wr[k];
    out[(size_t)m * 47 + t] = a;
  }
}

// ---------------------------------------------------------------------------
extern "C" void kernel_launch(void* const* d_in, const int* in_sizes, int n_in,
                              void* d_out, int out_size, void* d_ws,
                              size_t ws_size, hipStream_t stream) {
  const float* feats0 = (const float*)d_in[0];
  const float* feats1 = (const float*)d_in[1];
  const float* feats2 = (const float*)d_in[2];
  const float* nmask0 = (const float*)d_in[3];
  const float* nmask1 = (const float*)d_in[4];
  const float* nmask2 = (const float*)d_in[5];
  const int* nbmask0 = (const int*)d_in[6];
  const int* nbmask1 = (const int*)d_in[7];
  const float* emb_w = (const float*)d_in[8];
  const float* emb_b = (const float*)d_in[9];
  const float* sage_w = (const float*)d_in[10];
  const float* sage_b = (const float*)d_in[11];
  const float* qkv_w = (const float*)d_in[12];
  const float* qkv_b = (const float*)d_in[13];
  const float* out_w = (const float*)d_in[14];
  const float* out_b = (const float*)d_in[15];
  const float* n1_g = (const float*)d_in[16];
  const float* n1_b = (const float*)d_in[17];
  const float* n2_g = (const float*)d_in[18];
  const float* n2_b = (const float*)d_in[19];
  const float* ffn_w1 = (const float*)d_in[20];
  const float* ffn_b1 = (const float*)d_in[21];
  const float* ffn_w2 = (const float*)d_in[22];
  const float* ffn_b2 = (const float*)d_in[23];
  const float* cls_w = (const float*)d_in[24];
  const float* cls_b = (const float*)d_in[25];
  float* out = (float*)d_out;

  size_t off = 0;
  auto alloc = [&](size_t bytes) {
    void* r = (char*)d_ws + off;
    off += (bytes + 255) & ~(size_t)255;
    return r;
  };
  bf16_t* wemb = (bf16_t*)alloc((size_t)512 * 256 * 2);
  bf16_t* wsage = (bf16_t*)alloc((size_t)2 * 512 * 1024 * 2);
  bf16_t* wqkv = (bf16_t*)alloc((size_t)2 * 1536 * 512 * 2);
  bf16_t* wout = (bf16_t*)alloc((size_t)2 * 512 * 512 * 2);
  bf16_t* wf1 = (bf16_t*)alloc((size_t)2 * 1024 * 512 * 2);
  bf16_t* wf2 = (bf16_t*)alloc((size_t)2 * 512 * 1024 * 2);
  bf16_t* fcat = (bf16_t*)alloc((size_t)M_CAT * 256 * 2);   // feats1|feats0
  bf16_t* s_cat = (bf16_t*)alloc((size_t)2 * M_CAT * 512 * 2);
  bf16_t* agg_cat = s_cat + (size_t)M_CAT * 512;
  bf16_t* scat_o = (bf16_t*)alloc((size_t)M_CAT * 512 * 2); // s1b|s0b
  bf16_t* aggFb = (bf16_t*)alloc((size_t)4096 * 256 * 2);
  float* swv = (float*)alloc((size_t)4096 * 4);
  float* invd = (float*)alloc((size_t)4096 * 4);
  bf16_t* agg256 = (bf16_t*)alloc((size_t)256 * 512 * 2);
  bf16_t* s0f = (bf16_t*)alloc((size_t)256 * 512 * 2);
  bf16_t* tmpb = (bf16_t*)alloc((size_t)M_CAT * 512 * 2);
  bf16_t* h1 = (bf16_t*)alloc((size_t)M_CAT * 512 * 2);
  bf16_t* h2 = (bf16_t*)alloc((size_t)M_CAT * 512 * 2);
  bf16_t* qkb = (bf16_t*)alloc((size_t)M_CAT * 1024 * 2);
  bf16_t* vt = (bf16_t*)alloc((size_t)512 * M_CAT * 2);
  bf16_t* attno = (bf16_t*)alloc((size_t)M_CAT * 512 * 2);
  bf16_t* f1o = (bf16_t*)alloc((size_t)M_CAT * 1024 * 2);
  bf16_t* Ofb = (bf16_t*)alloc((size_t)NSPLIT * 4096 * 512 * 2);
  float* Ml = (float*)alloc((size_t)NSPLIT * 4 * 4096 * 2 * 4);

  // weight + feature conversion; feats1 -> fcat rows 0..4096, feats0 -> tail
  cvt_all<<<6336, 256, 0, stream>>>(emb_w, sage_w, qkv_w, out_w, ffn_w1,
                                    ffn_w2, feats0, feats1, wemb, wsage, wqkv,
                                    wout, wf1, wf2, fcat + (size_t)4096 * 256,
                                    fcat);

  // depth-2 masked feature aggregation
  agg_feats<<<1024, 256, 0, stream>>>(feats2, nbmask1, nmask2, aggFb, swv, invd);
  // merged embedding: rows 0..4352 -> s_cat; rows 4352..8448 -> agg_cat[0..4096]
  mgemm<64, 64, 6, false><<<dim3((M_CAT + M_BIG) / 64, 8), 256, 0, stream>>>(
      fcat, aggFb, wemb, emb_b, nullptr, nmask1, nmask0, swv, invd, s_cat,
      nullptr, M_CAT + M_BIG, M_BIG, 512, 256);
  // depth-0 aggregation of OLD s1 (agg_cat rows 4096..4352)
  agg_state<<<64, 256, 0, stream>>>(s_cat, nbmask0,
                                    agg_cat + (size_t)M_BIG * 512);

  // ---- layer 0, fused depth-1 (4096 rows) + depth-0 (256 rows) ----
  mgemm<64, 64, 0, true><<<dim3(M_CAT / 64, 8), 256, 0, stream>>>(
      s_cat, agg_cat, wsage, sage_b, nullptr, nullptr, nullptr, nullptr,
      nullptr, tmpb, nullptr, M_CAT, 0, 512, 1024);
  add_ln<<<M_CAT, 256, 0, stream>>>(s_cat, tmpb, n1_g, n1_b, h1);
  mgemm<64, 64, 5, false><<<dim3(M_CAT / 64, 24), 256, 0, stream>>>(
      h1, nullptr, wqkv, qkv_b, nullptr, nullptr, nullptr, nullptr, nullptr,
      qkb, vt, M_CAT, 0, 1536, 512);
  flashT<8, 2, NSPLIT><<<(M_BIG / 256) * 4 * NSPLIT, 512, 0, stream>>>(
      qkb, vt, nullptr, Ofb, Ml, M_BIG, M_CAT);
  flashT<4, 1, 1><<<(256 / 64) * 4, 256, 0, stream>>>(
      qkb + (size_t)M_BIG * 1024, vt + M_BIG, attno + (size_t)M_BIG * 512,
      nullptr, nullptr, 256, M_CAT);
  merge_attn<NSPLIT><<<M_BIG, 256, 0, stream>>>(Ofb, Ml, attno, M_BIG);
  mgemm<64, 64, 0, false><<<dim3(M_CAT / 64, 8), 256, 0, stream>>>(
      attno, nullptr, wout, out_b, nullptr, nullptr, nullptr, nullptr, nullptr,
      tmpb, nullptr, M_CAT, 0, 512, 512);
  add_ln<<<M_CAT, 256, 0, stream>>>(h1, tmpb, n2_g, n2_b, h2);
  mgemm<64, 64, 3, false><<<dim3(M_CAT / 64, 16), 256, 0, stream>>>(
      h2, nullptr, wf1, ffn_b1, nullptr, nullptr, nullptr, nullptr, nullptr,
      f1o, nullptr, M_CAT, 0, 1024, 512);
  mgemm<64, 64, 4, false><<<dim3(M_CAT / 64, 8), 256, 0, stream>>>(
      f1o, nullptr, wf2, ffn_b2, h2, nmask1, nmask0, nullptr, nullptr, scat_o,
      nullptr, M_CAT, M_BIG, 512, 1024);

  // ---- layer 1, depth 0 (n=256): sf = scat_o rows 4096.., children = rows 0..4096
  const bf16_t* s1b = scat_o;
  const bf16_t* s0b = scat_o + (size_t)M_BIG * 512;
  agg_state<<<64, 256, 0, stream>>>(s1b, nbmask0, agg256);
  const bf16_t* wsage1 = wsage + 512 * 1024;
  const bf16_t* wqkv1 = wqkv + 1536 * 512;
  const bf16_t* wout1 = wout + 512 * 512;
  const bf16_t* wf11 = wf1 + 1024 * 512;
  const bf16_t* wf21 = wf2 + 512 * 1024;
  mgemm<64, 64, 0, true><<<dim3(4, 8), 256, 0, stream>>>(
      s0b, agg256, wsage1, sage_b + 512, nullptr, nullptr, nullptr, nullptr,
      nullptr, tmpb, nullptr, 256, 0, 512, 1024);
  add_ln<<<256, 256, 0, stream>>>(s0b, tmpb, n1_g + 512, n1_b + 512, h1);
  mgemm<64, 64, 5, false><<<dim3(4, 24), 256, 0, stream>>>(
      h1, nullptr, wqkv1, qkv_b + 1536, nullptr, nullptr, nullptr, nullptr,
      nullptr, qkb, vt, 256, 0, 1536, 512);
  flashT<4, 1, 1><<<(256 / 64) * 4, 256, 0, stream>>>(
      qkb, vt, attno, nullptr, nullptr, 256, 256);
  mgemm<64, 64, 0, false><<<dim3(4, 8), 256, 0, stream>>>(
      attno, nullptr, wout1, out_b + 512, nullptr, nullptr, nullptr, nullptr,
      nullptr, tmpb, nullptr, 256, 0, 512, 512);
  add_ln<<<256, 256, 0, stream>>>(h1, tmpb, n2_g + 512, n2_b + 512, h2);
  mgemm<64, 64, 3, false><<<dim3(4, 16), 256, 0, stream>>>(
      h2, nullptr, wf11, ffn_b1 + 1024, nullptr, nullptr, nullptr, nullptr,
      nullptr, f1o, nullptr, 256, 0, 1024, 512);
  mgemm<64, 64, 4, false><<<dim3(4, 8), 256, 0, stream>>>(
      f1o, nullptr, wf21, ffn_b2 + 512, h2, nmask0, nmask0, nullptr, nullptr,
      s0f, nullptr, 256, 256, 512, 1024);

  cls_k<<<256, 256, 0, stream>>>(s0f, cls_w, cls_b, out);
}